// Round 1
// baseline (405.667 us; speedup 1.0000x reference)
//
#include <hip/hip_runtime.h>
#include <hip/hip_bf16.h>

// Problem constants
#define Hh 768
#define Ff 384      // H/2
#define Ee 9
#define Rr 10
#define Bb 8
#define Ss 4096
#define Nn_ENT 64
#define Pp 2016     // N*(N-1)/2
#define CH 16       // chunk size for seq prefix
#define NC 256      // S/CH

// ---------------------------------------------------------------------------
// Generic 64x64-tile f32 GEMM: C = [relu](A @ W + bias). A:(M,K) W:(K,N) row-major.
// grid.z applies wOff/cOff (used to do U and V halves in one launch).
// ---------------------------------------------------------------------------
template<bool RELU, bool OUT_BF16>
__global__ __launch_bounds__(256) void gemm_tiled(const float* __restrict__ A,
                                                  const float* __restrict__ W,
                                                  const float* __restrict__ bias,
                                                  void* __restrict__ Cv,
                                                  int Nn, int K,
                                                  long long wOff, long long cOff) {
  const float* Wp = W + (size_t)blockIdx.z * (size_t)wOff;
  __shared__ float As[16][68];
  __shared__ float Ws[16][68];
  const int t = threadIdx.x;
  const int row0 = blockIdx.x * 64, col0 = blockIdx.y * 64;
  const int tm = (t & 15) * 4, tn = (t >> 4) * 4;
  const int lr = t >> 2, lk = (t & 3) * 4;
  const int wk = t >> 4, wc = (t & 15) * 4;
  float acc[4][4] = {};
  const float* Arow = A + (size_t)(row0 + lr) * K + lk;
  for (int k0 = 0; k0 < K; k0 += 16) {
    float4 av = *(const float4*)(Arow + k0);
    As[lk + 0][lr] = av.x; As[lk + 1][lr] = av.y;
    As[lk + 2][lr] = av.z; As[lk + 3][lr] = av.w;
    *(float4*)&Ws[wk][wc] = *(const float4*)(Wp + (size_t)(k0 + wk) * Nn + col0 + wc);
    __syncthreads();
#pragma unroll
    for (int kk = 0; kk < 16; ++kk) {
      const float4 a = *(const float4*)&As[kk][tm];
      const float4 b = *(const float4*)&Ws[kk][tn];
      acc[0][0] = fmaf(a.x, b.x, acc[0][0]); acc[0][1] = fmaf(a.x, b.y, acc[0][1]);
      acc[0][2] = fmaf(a.x, b.z, acc[0][2]); acc[0][3] = fmaf(a.x, b.w, acc[0][3]);
      acc[1][0] = fmaf(a.y, b.x, acc[1][0]); acc[1][1] = fmaf(a.y, b.y, acc[1][1]);
      acc[1][2] = fmaf(a.y, b.z, acc[1][2]); acc[1][3] = fmaf(a.y, b.w, acc[1][3]);
      acc[2][0] = fmaf(a.z, b.x, acc[2][0]); acc[2][1] = fmaf(a.z, b.y, acc[2][1]);
      acc[2][2] = fmaf(a.z, b.z, acc[2][2]); acc[2][3] = fmaf(a.z, b.w, acc[2][3]);
      acc[3][0] = fmaf(a.w, b.x, acc[3][0]); acc[3][1] = fmaf(a.w, b.y, acc[3][1]);
      acc[3][2] = fmaf(a.w, b.z, acc[3][2]); acc[3][3] = fmaf(a.w, b.w, acc[3][3]);
    }
    __syncthreads();
  }
  float bvals[4];
#pragma unroll
  for (int j = 0; j < 4; ++j) bvals[j] = bias ? bias[col0 + tn + j] : 0.f;
#pragma unroll
  for (int i = 0; i < 4; ++i) {
    size_t base = (size_t)blockIdx.z * (size_t)cOff + (size_t)(row0 + tm + i) * Nn + col0 + tn;
    float v[4];
#pragma unroll
    for (int j = 0; j < 4; ++j) {
      float x = acc[i][j] + bvals[j];
      if (RELU) x = fmaxf(x, 0.f);
      v[j] = x;
    }
    if (OUT_BF16) {
      __hip_bfloat16* Cb = (__hip_bfloat16*)Cv;
#pragma unroll
      for (int j = 0; j < 4; ++j) Cb[base + j] = __float2bfloat16(v[j]);
    } else {
      float4 o; o.x = v[0]; o.y = v[1]; o.z = v[2]; o.w = v[3];
      *(float4*)((float*)Cv + base) = o;
    }
  }
}

// ---------------------------------------------------------------------------
// entity_logits = h(bf16) @ w2 + b2.  h:(32768,384), w2:(384,9).
// Block = 64 rows (4 waves x 16 rows); 4 lanes cooperate per row.
// ---------------------------------------------------------------------------
__global__ __launch_bounds__(256) void gemm2_k(const __hip_bfloat16* __restrict__ h,
                                               const float* __restrict__ w2,
                                               const float* __restrict__ b2,
                                               float* __restrict__ out) {
  __shared__ float w2s[Ff * Ee];
  __shared__ float b2s[Ee];
  const int t = threadIdx.x;
  for (int i = t; i < Ff * Ee; i += 256) w2s[i] = w2[i];
  if (t < Ee) b2s[t] = b2[t];
  __syncthreads();
  const int lane = t & 63, warp = t >> 6;
  const int row = blockIdx.x * 64 + warp * 16 + (lane >> 2);
  const int q = lane & 3;
  float acc[Ee];
#pragma unroll
  for (int e = 0; e < Ee; ++e) acc[e] = 0.f;
  const unsigned short* hr = (const unsigned short*)h + (size_t)row * Ff;
  for (int k0 = q * 4; k0 < Ff; k0 += 16) {
    ushort4 us = *(const ushort4*)(hr + k0);
    float x0 = __uint_as_float((unsigned)us.x << 16);
    float x1 = __uint_as_float((unsigned)us.y << 16);
    float x2 = __uint_as_float((unsigned)us.z << 16);
    float x3 = __uint_as_float((unsigned)us.w << 16);
#pragma unroll
    for (int e = 0; e < Ee; ++e) {
      acc[e] = fmaf(x0, w2s[(k0 + 0) * Ee + e], acc[e]);
      acc[e] = fmaf(x1, w2s[(k0 + 1) * Ee + e], acc[e]);
      acc[e] = fmaf(x2, w2s[(k0 + 2) * Ee + e], acc[e]);
      acc[e] = fmaf(x3, w2s[(k0 + 3) * Ee + e], acc[e]);
    }
  }
#pragma unroll
  for (int e = 0; e < Ee; ++e) {
    acc[e] += __shfl_xor(acc[e], 1);
    acc[e] += __shfl_xor(acc[e], 2);
  }
  if (q == 0) {
#pragma unroll
    for (int e = 0; e < Ee; ++e) out[(size_t)row * Ee + e] = acc[e] + b2s[e];
  }
}

// ---------------------------------------------------------------------------
// Chunk sums of seq over S (chunks of 16) -> Pc[b][c+1][h]
// ---------------------------------------------------------------------------
__global__ __launch_bounds__(256) void chunk_sums(const float* __restrict__ seq,
                                                  float* __restrict__ Pc) {
  const int b = blockIdx.z, c = blockIdx.y;
  const int hh = blockIdx.x * 256 + threadIdx.x;
  const float* p = seq + ((size_t)b * Ss + (size_t)c * CH) * Hh + hh;
  float acc = 0.f;
#pragma unroll
  for (int s = 0; s < CH; ++s) acc += p[(size_t)s * Hh];
  Pc[((size_t)b * (NC + 1) + c + 1) * Hh + hh] = acc;
}

// Prefix over chunks (in place): Pc[b][0]=0; Pc[b][c] = cumsum
__global__ __launch_bounds__(256) void chunk_prefix(float* __restrict__ Pc) {
  const int b = blockIdx.y;
  const int hh = blockIdx.x * 256 + threadIdx.x;
  float* p = Pc + (size_t)b * (NC + 1) * Hh + hh;
  p[0] = 0.f;
  float acc = 0.f;
  for (int c = 1; c <= NC; ++c) {
    acc += p[(size_t)c * Hh];
    p[(size_t)c * Hh] = acc;
  }
}

// ---------------------------------------------------------------------------
// entity_reprs[b][n][h] = (sum_{s in [start,end)} seq[b][s][h]) / max(end-start,1)
// via chunk-prefix diff + edge rows.
// ---------------------------------------------------------------------------
__global__ __launch_bounds__(256) void entity_reprs_k(const float* __restrict__ seq,
                                                      const float* __restrict__ Pc,
                                                      const int* __restrict__ spans,
                                                      float* __restrict__ reprs) {
  const int bn = blockIdx.x;
  const int b = bn >> 6;
  const int start = spans[bn * 2], end = spans[bn * 2 + 1];
  const int cnt = max(end - start, 1);
  const float inv = 1.0f / (float)cnt;
  const int cs = (start + CH - 1) >> 4, ce = end >> 4;
  const float* seqb = seq + (size_t)b * Ss * Hh;
  const float* Pcb = Pc + (size_t)b * (NC + 1) * Hh;
  for (int hh = threadIdx.x; hh < Hh; hh += 256) {
    float acc = 0.f;
    if (cs <= ce) {
      acc = Pcb[(size_t)ce * Hh + hh] - Pcb[(size_t)cs * Hh + hh];
      for (int s = start; s < cs * CH; ++s) acc += seqb[(size_t)s * Hh + hh];
      for (int s = ce * CH; s < end; ++s) acc += seqb[(size_t)s * Hh + hh];
    } else {
      for (int s = start; s < end; ++s) acc += seqb[(size_t)s * Hh + hh];
    }
    reprs[(size_t)bn * Hh + hh] = acc * inv;
  }
}

// ---------------------------------------------------------------------------
// pooled argmax: entity_types[bn] = argmax_e sum_{s in span} entity_logits[b][s][e]
// (positive 1/count scaling doesn't change argmax). One wave per entity.
// ---------------------------------------------------------------------------
__global__ __launch_bounds__(256) void pooled_argmax(const float* __restrict__ elog,
                                                     const int* __restrict__ spans,
                                                     float* __restrict__ etypes) {
  const int bn = blockIdx.x * 4 + (threadIdx.x >> 6);
  const int lane = threadIdx.x & 63;
  const int b = bn >> 6;
  const int start = spans[bn * 2], end = spans[bn * 2 + 1];
  float acc[Ee];
#pragma unroll
  for (int e = 0; e < Ee; ++e) acc[e] = 0.f;
  const float* p = elog + (size_t)b * Ss * Ee;
  for (int s = start + lane; s < end; s += 64) {
    const float* q = p + (size_t)s * Ee;
#pragma unroll
    for (int e = 0; e < Ee; ++e) acc[e] += q[e];
  }
#pragma unroll
  for (int off = 32; off; off >>= 1)
#pragma unroll
    for (int e = 0; e < Ee; ++e) acc[e] += __shfl_down(acc[e], off);
  if (lane == 0) {
    int best = 0; float bv = acc[0];
#pragma unroll
    for (int e = 1; e < Ee; ++e) if (acc[e] > bv) { bv = acc[e]; best = e; }
    etypes[bn] = (float)best;
  }
}

// ---------------------------------------------------------------------------
// relations: logits[p][r] = sum_k relu(U[b,i,k]+V[b,j,k]+rb1[k]) * rw2[k][r] + rb2[r]
// One wave per (b,p). U at UV[0..], V at UV[512*768..].
// ---------------------------------------------------------------------------
__global__ __launch_bounds__(256) void relations_k(const float* __restrict__ UV,
                                                   const float* __restrict__ rb1,
                                                   const float* __restrict__ rw2,
                                                   const float* __restrict__ rb2,
                                                   float* __restrict__ rlogits,
                                                   float* __restrict__ rtypes) {
  const int p = blockIdx.x * 4 + (threadIdx.x >> 6);
  const int lane = threadIdx.x & 63;
  const int b = p / Pp, pp = p % Pp;
  int i = 0, off = 0;
  while (off + (Nn_ENT - 1 - i) <= pp) { off += Nn_ENT - 1 - i; ++i; }
  const int j = i + 1 + (pp - off);
  const float* u = UV + ((size_t)b * Nn_ENT + i) * Hh;
  const float* v = UV + (size_t)512 * Hh + ((size_t)b * Nn_ENT + j) * Hh;
  float acc[Rr];
#pragma unroll
  for (int r = 0; r < Rr; ++r) acc[r] = 0.f;
  for (int k = lane; k < Hh; k += 64) {
    float x = fmaxf(u[k] + v[k] + rb1[k], 0.f);
    const float* w = rw2 + (size_t)k * Rr;
#pragma unroll
    for (int r = 0; r < Rr; ++r) acc[r] = fmaf(x, w[r], acc[r]);
  }
#pragma unroll
  for (int off2 = 32; off2; off2 >>= 1)
#pragma unroll
    for (int r = 0; r < Rr; ++r) acc[r] += __shfl_down(acc[r], off2);
  if (lane == 0) {
    int best = 0; float bv = acc[0] + rb2[0];
    rlogits[(size_t)p * Rr + 0] = bv;
#pragma unroll
    for (int r = 1; r < Rr; ++r) {
      float val = acc[r] + rb2[r];
      rlogits[(size_t)p * Rr + r] = val;
      if (val > bv) { bv = val; best = r; }
    }
    rtypes[p] = (float)best;
  }
}

// ---------------------------------------------------------------------------
extern "C" void kernel_launch(void* const* d_in, const int* in_sizes, int n_in,
                              void* d_out, int out_size, void* d_ws, size_t ws_size,
                              hipStream_t stream) {
  const float* seq   = (const float*)d_in[0];
  const int*   spans = (const int*)d_in[2];
  const float* w1    = (const float*)d_in[3];
  const float* b1    = (const float*)d_in[4];
  const float* w2    = (const float*)d_in[5];
  const float* b2    = (const float*)d_in[6];
  const float* rw1   = (const float*)d_in[7];
  const float* rb1   = (const float*)d_in[8];
  const float* rw2   = (const float*)d_in[9];
  const float* rb2   = (const float*)d_in[10];

  float* out_elog = (float*)d_out;               // (B,S,E)   294912
  float* out_rlog = out_elog + 294912;           // (B,P,R)   161280
  float* out_repr = out_rlog + 161280;           // (B,N,H)   393216
  float* out_etyp = out_repr + 393216;           // (B,N)     512
  float* out_rtyp = out_etyp + 512;              // (B,P)     16128

  // workspace: h (bf16) | Pc (f32) | UV (f32)
  __hip_bfloat16* ws_h = (__hip_bfloat16*)d_ws;                       // 32768*384*2B = 25165824
  float* ws_pc = (float*)((char*)d_ws + 25165824);                    // 8*257*768*4B = 6316032
  float* ws_uv = (float*)((char*)d_ws + 25165824 + 6316032);          // 2*512*768*4B = 3145728

  // 1) h = relu(seq @ w1 + b1)  [f32 compute, bf16 store]
  gemm_tiled<true, true><<<dim3(512, 6, 1), 256, 0, stream>>>(
      seq, w1, b1, (void*)ws_h, Ff, Hh, 0LL, 0LL);
  // 2) entity_logits = h @ w2 + b2
  gemm2_k<<<512, 256, 0, stream>>>(ws_h, w2, b2, out_elog);
  // 3) chunk sums + prefix of seq over S
  chunk_sums<<<dim3(3, NC, Bb), 256, 0, stream>>>(seq, ws_pc);
  chunk_prefix<<<dim3(3, Bb, 1), 256, 0, stream>>>(ws_pc);
  // 4) entity_reprs
  entity_reprs_k<<<512, 256, 0, stream>>>(seq, ws_pc, spans, out_repr);
  // 5) U,V = reprs @ rw1 halves  (z=0 -> U, z=1 -> V)
  gemm_tiled<false, false><<<dim3(8, 12, 2), 256, 0, stream>>>(
      out_repr, rw1, nullptr, (void*)ws_uv, Hh, Hh, (long long)Hh * Hh, (long long)512 * Hh);
  // 6) entity_types via pooled-logits argmax
  pooled_argmax<<<128, 256, 0, stream>>>(out_elog, spans, out_etyp);
  // 7) relation logits + types
  relations_k<<<4032, 256, 0, stream>>>(ws_uv, rb1, rw2, rb2, out_rlog, out_rtyp);
}

// Round 2
// 327.856 us; speedup vs baseline: 1.2373x; 1.2373x over previous
//
#include <hip/hip_runtime.h>
#include <hip/hip_bf16.h>

// Problem constants
#define Hh 768
#define Ff 384      // H/2
#define Ee 9
#define Rr 10
#define Bb 8
#define Ss 4096
#define Nn_ENT 64
#define Pp 2016     // N*(N-1)/2
#define CH 16       // chunk size for seq prefix
#define NC 256      // S/CH

typedef short bf16x8 __attribute__((ext_vector_type(8)));
typedef float f32x4 __attribute__((ext_vector_type(4)));

#define BM 128
#define BN 128
#define BK 64
#define LDK 72   // padded LDS stride in bf16 elems (144 B, 16B-aligned)

// ---------------------------------------------------------------------------
// w1 (768x384 f32, k-major) -> Wt (384x768 bf16, col-major rows) via LDS tile
// ---------------------------------------------------------------------------
__global__ __launch_bounds__(256) void transpose_w1(const float* __restrict__ w1,
                                                    unsigned short* __restrict__ wt) {
  __shared__ unsigned short tile[64][65];
  const int bk = blockIdx.x * 64;   // k block (12)
  const int bc = blockIdx.y * 64;   // col block (6)
  const int c = threadIdx.x & 63, kq = threadIdx.x >> 6;
#pragma unroll
  for (int i = 0; i < 16; ++i) {
    int k = kq * 16 + i;
    float v = w1[(size_t)(bk + k) * Ff + bc + c];
    tile[c][k] = __bfloat16_as_ushort(__float2bfloat16(v));
  }
  __syncthreads();
  const int k2 = threadIdx.x & 63, cq = threadIdx.x >> 6;
#pragma unroll
  for (int i = 0; i < 16; ++i) {
    int c2 = cq * 16 + i;
    wt[(size_t)(bc + c2) * Hh + bk + k2] = tile[c2][k2];
  }
}

// ---------------------------------------------------------------------------
// GEMM1: h = relu(seq @ w1 + b1) via bf16 MFMA, fused f32->bf16 staging.
// A: (32768,768) f32. Wt: (384,768) bf16 (pre-transposed). H out: bf16 (32768,384).
// 128x128 tile, BK=64, 4 waves 2x2 (64x64 each), 16x16x32 MFMA.
// Grid 768 = 256 m-tiles x 3 n-tiles, XCD-chunked swizzle (n fastest).
// ---------------------------------------------------------------------------
__global__ __launch_bounds__(256) void gemm1_mfma(const float* __restrict__ A,
                                                  const unsigned short* __restrict__ Wt,
                                                  const float* __restrict__ b1,
                                                  unsigned short* __restrict__ H) {
  __shared__ short As[BM][LDK];
  __shared__ short Bs[BN][LDK];
  const int wg = blockIdx.x;
  const int lin = (wg & 7) * 96 + (wg >> 3);   // 768 % 8 == 0 -> bijective
  const int mt = lin / 3, nt = lin % 3;
  const int row0 = mt * BM, col0 = nt * BN;
  const int t = threadIdx.x;
  const int wid = t >> 6, lane = t & 63;
  const int wm = wid >> 1, wn = wid & 1;
  const int fr = lane & 15, fk = (lane >> 4) * 8;

  const int srow = t >> 1;            // 0..127
  const int skh = (t & 1) * 32;       // 0 or 32
  const float* aptr = A + (size_t)(row0 + srow) * Hh + skh;
  const unsigned short* bptr = Wt + (size_t)(col0 + srow) * Hh + skh;

  f32x4 acc[4][4] = {};

  for (int k0 = 0; k0 < Hh; k0 += BK) {
    // stage A: 32 f32 -> 32 bf16 per thread
    {
      const float* ap = aptr + k0;
#pragma unroll
      for (int i = 0; i < 4; ++i) {
        float4 v0 = ((const float4*)ap)[2 * i];
        float4 v1 = ((const float4*)ap)[2 * i + 1];
        union { bf16x8 v; __hip_bfloat162 h[4]; } u;
        u.h[0] = __float22bfloat162_rn(float2{v0.x, v0.y});
        u.h[1] = __float22bfloat162_rn(float2{v0.z, v0.w});
        u.h[2] = __float22bfloat162_rn(float2{v1.x, v1.y});
        u.h[3] = __float22bfloat162_rn(float2{v1.z, v1.w});
        *(bf16x8*)&As[srow][skh + 8 * i] = u.v;
      }
      const unsigned short* bp = bptr + k0;
#pragma unroll
      for (int i = 0; i < 4; ++i)
        *(bf16x8*)&Bs[srow][skh + 8 * i] = *(const bf16x8*)(bp + 8 * i);
    }
    __syncthreads();
#pragma unroll
    for (int kk = 0; kk < 2; ++kk) {
      bf16x8 af[4], bfr[4];
#pragma unroll
      for (int m = 0; m < 4; ++m)
        af[m] = *(const bf16x8*)&As[wm * 64 + m * 16 + fr][kk * 32 + fk];
#pragma unroll
      for (int n = 0; n < 4; ++n)
        bfr[n] = *(const bf16x8*)&Bs[wn * 64 + n * 16 + fr][kk * 32 + fk];
#pragma unroll
      for (int m = 0; m < 4; ++m)
#pragma unroll
        for (int n = 0; n < 4; ++n)
          acc[m][n] = __builtin_amdgcn_mfma_f32_16x16x32_bf16(af[m], bfr[n], acc[m][n], 0, 0, 0);
    }
    __syncthreads();
  }
  // epilogue: bias + relu, store bf16. C/D: col=lane&15, row=(lane>>4)*4+reg
#pragma unroll
  for (int n = 0; n < 4; ++n) {
    const int col = col0 + wn * 64 + n * 16 + fr;
    const float bias = b1[col];
#pragma unroll
    for (int m = 0; m < 4; ++m) {
      const int rbase = row0 + wm * 64 + m * 16 + (lane >> 4) * 4;
#pragma unroll
      for (int j = 0; j < 4; ++j) {
        float x = fmaxf(acc[m][n][j] + bias, 0.f);
        H[(size_t)(rbase + j) * Ff + col] = __bfloat16_as_ushort(__float2bfloat16(x));
      }
    }
  }
}

// ---------------------------------------------------------------------------
// Generic 64x64-tile f32 GEMM (kept for the small U/V projection).
// ---------------------------------------------------------------------------
template<bool RELU, bool OUT_BF16>
__global__ __launch_bounds__(256) void gemm_tiled(const float* __restrict__ A,
                                                  const float* __restrict__ W,
                                                  const float* __restrict__ bias,
                                                  void* __restrict__ Cv,
                                                  int Nn, int K,
                                                  long long wOff, long long cOff) {
  const float* Wp = W + (size_t)blockIdx.z * (size_t)wOff;
  __shared__ float Ast[16][68];
  __shared__ float Wst[16][68];
  const int t = threadIdx.x;
  const int row0 = blockIdx.x * 64, col0 = blockIdx.y * 64;
  const int tm = (t & 15) * 4, tn = (t >> 4) * 4;
  const int lr = t >> 2, lk = (t & 3) * 4;
  const int wk = t >> 4, wc = (t & 15) * 4;
  float acc[4][4] = {};
  const float* Arow = A + (size_t)(row0 + lr) * K + lk;
  for (int k0 = 0; k0 < K; k0 += 16) {
    float4 av = *(const float4*)(Arow + k0);
    Ast[lk + 0][lr] = av.x; Ast[lk + 1][lr] = av.y;
    Ast[lk + 2][lr] = av.z; Ast[lk + 3][lr] = av.w;
    *(float4*)&Wst[wk][wc] = *(const float4*)(Wp + (size_t)(k0 + wk) * Nn + col0 + wc);
    __syncthreads();
#pragma unroll
    for (int kk = 0; kk < 16; ++kk) {
      const float4 a = *(const float4*)&Ast[kk][tm];
      const float4 b = *(const float4*)&Wst[kk][tn];
      acc[0][0] = fmaf(a.x, b.x, acc[0][0]); acc[0][1] = fmaf(a.x, b.y, acc[0][1]);
      acc[0][2] = fmaf(a.x, b.z, acc[0][2]); acc[0][3] = fmaf(a.x, b.w, acc[0][3]);
      acc[1][0] = fmaf(a.y, b.x, acc[1][0]); acc[1][1] = fmaf(a.y, b.y, acc[1][1]);
      acc[1][2] = fmaf(a.y, b.z, acc[1][2]); acc[1][3] = fmaf(a.y, b.w, acc[1][3]);
      acc[2][0] = fmaf(a.z, b.x, acc[2][0]); acc[2][1] = fmaf(a.z, b.y, acc[2][1]);
      acc[2][2] = fmaf(a.z, b.z, acc[2][2]); acc[2][3] = fmaf(a.z, b.w, acc[2][3]);
      acc[3][0] = fmaf(a.w, b.x, acc[3][0]); acc[3][1] = fmaf(a.w, b.y, acc[3][1]);
      acc[3][2] = fmaf(a.w, b.z, acc[3][2]); acc[3][3] = fmaf(a.w, b.w, acc[3][3]);
    }
    __syncthreads();
  }
  float bvals[4];
#pragma unroll
  for (int j = 0; j < 4; ++j) bvals[j] = bias ? bias[col0 + tn + j] : 0.f;
#pragma unroll
  for (int i = 0; i < 4; ++i) {
    size_t base = (size_t)blockIdx.z * (size_t)cOff + (size_t)(row0 + tm + i) * Nn + col0 + tn;
    float v[4];
#pragma unroll
    for (int j = 0; j < 4; ++j) {
      float x = acc[i][j] + bvals[j];
      if (RELU) x = fmaxf(x, 0.f);
      v[j] = x;
    }
    if (OUT_BF16) {
      __hip_bfloat16* Cb = (__hip_bfloat16*)Cv;
#pragma unroll
      for (int j = 0; j < 4; ++j) Cb[base + j] = __float2bfloat16(v[j]);
    } else {
      float4 o; o.x = v[0]; o.y = v[1]; o.z = v[2]; o.w = v[3];
      *(float4*)((float*)Cv + base) = o;
    }
  }
}

// ---------------------------------------------------------------------------
// entity_logits = h(bf16) @ w2 + b2.
// ---------------------------------------------------------------------------
__global__ __launch_bounds__(256) void gemm2_k(const __hip_bfloat16* __restrict__ h,
                                               const float* __restrict__ w2,
                                               const float* __restrict__ b2,
                                               float* __restrict__ out) {
  __shared__ float w2s[Ff * Ee];
  __shared__ float b2s[Ee];
  const int t = threadIdx.x;
  for (int i = t; i < Ff * Ee; i += 256) w2s[i] = w2[i];
  if (t < Ee) b2s[t] = b2[t];
  __syncthreads();
  const int lane = t & 63, warp = t >> 6;
  const int row = blockIdx.x * 64 + warp * 16 + (lane >> 2);
  const int q = lane & 3;
  float acc[Ee];
#pragma unroll
  for (int e = 0; e < Ee; ++e) acc[e] = 0.f;
  const unsigned short* hr = (const unsigned short*)h + (size_t)row * Ff;
  for (int k0 = q * 4; k0 < Ff; k0 += 16) {
    ushort4 us = *(const ushort4*)(hr + k0);
    float x0 = __uint_as_float((unsigned)us.x << 16);
    float x1 = __uint_as_float((unsigned)us.y << 16);
    float x2 = __uint_as_float((unsigned)us.z << 16);
    float x3 = __uint_as_float((unsigned)us.w << 16);
#pragma unroll
    for (int e = 0; e < Ee; ++e) {
      acc[e] = fmaf(x0, w2s[(k0 + 0) * Ee + e], acc[e]);
      acc[e] = fmaf(x1, w2s[(k0 + 1) * Ee + e], acc[e]);
      acc[e] = fmaf(x2, w2s[(k0 + 2) * Ee + e], acc[e]);
      acc[e] = fmaf(x3, w2s[(k0 + 3) * Ee + e], acc[e]);
    }
  }
#pragma unroll
  for (int e = 0; e < Ee; ++e) {
    acc[e] += __shfl_xor(acc[e], 1);
    acc[e] += __shfl_xor(acc[e], 2);
  }
  if (q == 0) {
#pragma unroll
    for (int e = 0; e < Ee; ++e) out[(size_t)row * Ee + e] = acc[e] + b2s[e];
  }
}

// ---------------------------------------------------------------------------
// Chunk sums of seq over S (chunks of 16) -> Pc[b][c][h]  (float4 vectorized)
// ---------------------------------------------------------------------------
__global__ __launch_bounds__(192) void chunk_sums(const float* __restrict__ seq,
                                                  float* __restrict__ Pc) {
  const int c = blockIdx.x, b = blockIdx.y;
  const int t = threadIdx.x;   // 192 threads x float4 = 768
  const float4* p = (const float4*)(seq + ((size_t)b * Ss + (size_t)c * CH) * Hh) + t;
  float4 acc = {0.f, 0.f, 0.f, 0.f};
#pragma unroll
  for (int s = 0; s < CH; ++s) {
    float4 v = p[(size_t)s * (Hh / 4)];
    acc.x += v.x; acc.y += v.y; acc.z += v.z; acc.w += v.w;
  }
  ((float4*)(Pc + ((size_t)b * NC + c) * Hh))[t] = acc;
}

// ---------------------------------------------------------------------------
// entity_reprs via direct chunk-range sum (no serial prefix) + edge rows.
// ---------------------------------------------------------------------------
__global__ __launch_bounds__(256) void entity_reprs_k(const float* __restrict__ seq,
                                                      const float* __restrict__ Pc,
                                                      const int* __restrict__ spans,
                                                      float* __restrict__ reprs) {
  const int bn = blockIdx.x;
  const int b = bn >> 6;
  const int start = spans[bn * 2], end = spans[bn * 2 + 1];
  const int cnt = max(end - start, 1);
  const float inv = 1.0f / (float)cnt;
  const int cs = (start + CH - 1) >> 4, ce = end >> 4;
  const float* seqb = seq + (size_t)b * Ss * Hh;
  const float* Pcb = Pc + (size_t)b * NC * Hh;
  for (int hh = threadIdx.x; hh < Hh; hh += 256) {
    float acc = 0.f;
    if (cs <= ce) {
      for (int c = cs; c < ce; ++c) acc += Pcb[(size_t)c * Hh + hh];
      for (int s = start; s < cs * CH; ++s) acc += seqb[(size_t)s * Hh + hh];
      for (int s = ce * CH; s < end; ++s) acc += seqb[(size_t)s * Hh + hh];
    } else {
      for (int s = start; s < end; ++s) acc += seqb[(size_t)s * Hh + hh];
    }
    reprs[(size_t)bn * Hh + hh] = acc * inv;
  }
}

// ---------------------------------------------------------------------------
// pooled argmax (scaling by 1/count is positive -> argmax invariant)
// ---------------------------------------------------------------------------
__global__ __launch_bounds__(256) void pooled_argmax(const float* __restrict__ elog,
                                                     const int* __restrict__ spans,
                                                     float* __restrict__ etypes) {
  const int bn = blockIdx.x * 4 + (threadIdx.x >> 6);
  const int lane = threadIdx.x & 63;
  const int b = bn >> 6;
  const int start = spans[bn * 2], end = spans[bn * 2 + 1];
  float acc[Ee];
#pragma unroll
  for (int e = 0; e < Ee; ++e) acc[e] = 0.f;
  const float* p = elog + (size_t)b * Ss * Ee;
  for (int s = start + lane; s < end; s += 64) {
    const float* q = p + (size_t)s * Ee;
#pragma unroll
    for (int e = 0; e < Ee; ++e) acc[e] += q[e];
  }
#pragma unroll
  for (int off = 32; off; off >>= 1)
#pragma unroll
    for (int e = 0; e < Ee; ++e) acc[e] += __shfl_down(acc[e], off);
  if (lane == 0) {
    int best = 0; float bv = acc[0];
#pragma unroll
    for (int e = 1; e < Ee; ++e) if (acc[e] > bv) { bv = acc[e]; best = e; }
    etypes[bn] = (float)best;
  }
}

// ---------------------------------------------------------------------------
// relations: one wave per (b,p); U/V factorization of the concat GEMM.
// ---------------------------------------------------------------------------
__global__ __launch_bounds__(256) void relations_k(const float* __restrict__ UV,
                                                   const float* __restrict__ rb1,
                                                   const float* __restrict__ rw2,
                                                   const float* __restrict__ rb2,
                                                   float* __restrict__ rlogits,
                                                   float* __restrict__ rtypes) {
  const int p = blockIdx.x * 4 + (threadIdx.x >> 6);
  const int lane = threadIdx.x & 63;
  const int b = p / Pp, pp = p % Pp;
  int i = 0, off = 0;
  while (off + (Nn_ENT - 1 - i) <= pp) { off += Nn_ENT - 1 - i; ++i; }
  const int j = i + 1 + (pp - off);
  const float* u = UV + ((size_t)b * Nn_ENT + i) * Hh;
  const float* v = UV + (size_t)512 * Hh + ((size_t)b * Nn_ENT + j) * Hh;
  float acc[Rr];
#pragma unroll
  for (int r = 0; r < Rr; ++r) acc[r] = 0.f;
  for (int k = lane; k < Hh; k += 64) {
    float x = fmaxf(u[k] + v[k] + rb1[k], 0.f);
    const float* w = rw2 + (size_t)k * Rr;
#pragma unroll
    for (int r = 0; r < Rr; ++r) acc[r] = fmaf(x, w[r], acc[r]);
  }
#pragma unroll
  for (int off2 = 32; off2; off2 >>= 1)
#pragma unroll
    for (int r = 0; r < Rr; ++r) acc[r] += __shfl_down(acc[r], off2);
  if (lane == 0) {
    int best = 0; float bv = acc[0] + rb2[0];
    rlogits[(size_t)p * Rr + 0] = bv;
#pragma unroll
    for (int r = 1; r < Rr; ++r) {
      float val = acc[r] + rb2[r];
      rlogits[(size_t)p * Rr + r] = val;
      if (val > bv) { bv = val; best = r; }
    }
    rtypes[p] = (float)best;
  }
}

// ---------------------------------------------------------------------------
extern "C" void kernel_launch(void* const* d_in, const int* in_sizes, int n_in,
                              void* d_out, int out_size, void* d_ws, size_t ws_size,
                              hipStream_t stream) {
  const float* seq   = (const float*)d_in[0];
  const int*   spans = (const int*)d_in[2];
  const float* w1    = (const float*)d_in[3];
  const float* b1    = (const float*)d_in[4];
  const float* w2    = (const float*)d_in[5];
  const float* b2    = (const float*)d_in[6];
  const float* rw1   = (const float*)d_in[7];
  const float* rb1   = (const float*)d_in[8];
  const float* rw2   = (const float*)d_in[9];
  const float* rb2   = (const float*)d_in[10];

  float* out_elog = (float*)d_out;               // (B,S,E)   294912
  float* out_rlog = out_elog + 294912;           // (B,P,R)   161280
  float* out_repr = out_rlog + 161280;           // (B,N,H)   393216
  float* out_etyp = out_repr + 393216;           // (B,N)     512
  float* out_rtyp = out_etyp + 512;              // (B,P)     16128

  // workspace: h (bf16) | Pc (f32) | UV (f32) | Wt (bf16)
  __hip_bfloat16* ws_h  = (__hip_bfloat16*)d_ws;                           // 25165824 B
  float*          ws_pc = (float*)((char*)d_ws + 25165824);                // 8*256*768*4 = 6291456 B
  float*          ws_uv = (float*)((char*)d_ws + 25165824 + 6291456);      // 3145728 B
  unsigned short* ws_wt = (unsigned short*)((char*)d_ws + 25165824 + 6291456 + 3145728); // 589824 B

  // 0) w1 -> bf16 transposed
  transpose_w1<<<dim3(12, 6), 256, 0, stream>>>(w1, ws_wt);
  // 1) h = relu(seq @ w1 + b1) via bf16 MFMA
  gemm1_mfma<<<768, 256, 0, stream>>>(seq, ws_wt, b1, (unsigned short*)ws_h);
  // 2) entity_logits = h @ w2 + b2
  gemm2_k<<<512, 256, 0, stream>>>(ws_h, w2, b2, out_elog);
  // 3) chunk sums of seq
  chunk_sums<<<dim3(NC, Bb), 192, 0, stream>>>(seq, ws_pc);
  // 4) entity_reprs (direct chunk-range sum)
  entity_reprs_k<<<512, 256, 0, stream>>>(seq, ws_pc, spans, out_repr);
  // 5) U,V = reprs @ rw1 halves (f32, small)
  gemm_tiled<false, false><<<dim3(8, 12, 2), 256, 0, stream>>>(
      out_repr, rw1, nullptr, (void*)ws_uv, Hh, Hh, (long long)Hh * Hh, (long long)512 * Hh);
  // 6) entity_types via pooled-logits argmax
  pooled_argmax<<<128, 256, 0, stream>>>(out_elog, spans, out_etyp);
  // 7) relation logits + types
  relations_k<<<4032, 256, 0, stream>>>(ws_uv, rb1, rw2, rb2, out_rlog, out_rtyp);
}

// Round 3
// 204.809 us; speedup vs baseline: 1.9807x; 1.6008x over previous
//
#include <hip/hip_runtime.h>
#include <hip/hip_bf16.h>

// Problem constants
#define Hh 768
#define Ff 384      // H/2
#define Ee 9
#define Rr 10
#define Bb 8
#define Ss 4096
#define Nn_ENT 64
#define Pp 2016     // N*(N-1)/2
#define CH 16       // chunk size for seq prefix
#define NC 256      // S/CH

typedef short bf16x8 __attribute__((ext_vector_type(8)));
typedef float f32x4 __attribute__((ext_vector_type(4)));

#define BM 128
#define BN 128
#define BK 64
#define LDK 72   // padded LDS stride in bf16 elems (144 B, 16B-aligned)

// ---------------------------------------------------------------------------
// w1 (768x384 f32, k-major) -> Wt (384x768 bf16) via LDS tile transpose
// ---------------------------------------------------------------------------
__global__ __launch_bounds__(256) void transpose_w1(const float* __restrict__ w1,
                                                    unsigned short* __restrict__ wt) {
  __shared__ unsigned short tile[64][65];
  const int bk = blockIdx.x * 64;   // k block (12)
  const int bc = blockIdx.y * 64;   // col block (6)
  const int c = threadIdx.x & 63, kq = threadIdx.x >> 6;
#pragma unroll
  for (int i = 0; i < 16; ++i) {
    int k = kq * 16 + i;
    float v = w1[(size_t)(bk + k) * Ff + bc + c];
    tile[c][k] = __bfloat16_as_ushort(__float2bfloat16(v));
  }
  __syncthreads();
  const int k2 = threadIdx.x & 63, cq = threadIdx.x >> 6;
#pragma unroll
  for (int i = 0; i < 16; ++i) {
    int c2 = cq * 16 + i;
    wt[(size_t)(bc + c2) * Hh + bk + k2] = tile[c2][k2];
  }
}

// ---------------------------------------------------------------------------
// GEMM1: h = relu(seq @ w1 + b1) via bf16 MFMA, fused f32->bf16 staging.
// 128x128 tile, BK=64, 4 waves 2x2 (64x64 each), 16x16x32 MFMA.
// ---------------------------------------------------------------------------
__global__ __launch_bounds__(256) void gemm1_mfma(const float* __restrict__ A,
                                                  const unsigned short* __restrict__ Wt,
                                                  const float* __restrict__ b1,
                                                  unsigned short* __restrict__ H) {
  __shared__ short As[BM][LDK];
  __shared__ short Bs[BN][LDK];
  const int wg = blockIdx.x;
  const int lin = (wg & 7) * 96 + (wg >> 3);   // 768 % 8 == 0 -> bijective
  const int mt = lin / 3, nt = lin % 3;
  const int row0 = mt * BM, col0 = nt * BN;
  const int t = threadIdx.x;
  const int wid = t >> 6, lane = t & 63;
  const int wm = wid >> 1, wn = wid & 1;
  const int fr = lane & 15, fk = (lane >> 4) * 8;

  const int srow = t >> 1;            // 0..127
  const int skh = (t & 1) * 32;       // 0 or 32
  const float* aptr = A + (size_t)(row0 + srow) * Hh + skh;
  const unsigned short* bptr = Wt + (size_t)(col0 + srow) * Hh + skh;

  f32x4 acc[4][4] = {};

  for (int k0 = 0; k0 < Hh; k0 += BK) {
    {
      const float* ap = aptr + k0;
#pragma unroll
      for (int i = 0; i < 4; ++i) {
        float4 v0 = ((const float4*)ap)[2 * i];
        float4 v1 = ((const float4*)ap)[2 * i + 1];
        union { bf16x8 v; __hip_bfloat162 h[4]; } u;
        u.h[0] = __float22bfloat162_rn(float2{v0.x, v0.y});
        u.h[1] = __float22bfloat162_rn(float2{v0.z, v0.w});
        u.h[2] = __float22bfloat162_rn(float2{v1.x, v1.y});
        u.h[3] = __float22bfloat162_rn(float2{v1.z, v1.w});
        *(bf16x8*)&As[srow][skh + 8 * i] = u.v;
      }
      const unsigned short* bp = bptr + k0;
#pragma unroll
      for (int i = 0; i < 4; ++i)
        *(bf16x8*)&Bs[srow][skh + 8 * i] = *(const bf16x8*)(bp + 8 * i);
    }
    __syncthreads();
#pragma unroll
    for (int kk = 0; kk < 2; ++kk) {
      bf16x8 af[4], bfr[4];
#pragma unroll
      for (int m = 0; m < 4; ++m)
        af[m] = *(const bf16x8*)&As[wm * 64 + m * 16 + fr][kk * 32 + fk];
#pragma unroll
      for (int n = 0; n < 4; ++n)
        bfr[n] = *(const bf16x8*)&Bs[wn * 64 + n * 16 + fr][kk * 32 + fk];
#pragma unroll
      for (int m = 0; m < 4; ++m)
#pragma unroll
        for (int n = 0; n < 4; ++n)
          acc[m][n] = __builtin_amdgcn_mfma_f32_16x16x32_bf16(af[m], bfr[n], acc[m][n], 0, 0, 0);
    }
    __syncthreads();
  }
#pragma unroll
  for (int n = 0; n < 4; ++n) {
    const int col = col0 + wn * 64 + n * 16 + fr;
    const float bias = b1[col];
#pragma unroll
    for (int m = 0; m < 4; ++m) {
      const int rbase = row0 + wm * 64 + m * 16 + (lane >> 4) * 4;
#pragma unroll
      for (int j = 0; j < 4; ++j) {
        float x = fmaxf(acc[m][n][j] + bias, 0.f);
        H[(size_t)(rbase + j) * Ff + col] = __bfloat16_as_ushort(__float2bfloat16(x));
      }
    }
  }
}

// ---------------------------------------------------------------------------
// Generic 64x64-tile f32 GEMM (kept for the small U/V projection).
// ---------------------------------------------------------------------------
template<bool RELU, bool OUT_BF16>
__global__ __launch_bounds__(256) void gemm_tiled(const float* __restrict__ A,
                                                  const float* __restrict__ W,
                                                  const float* __restrict__ bias,
                                                  void* __restrict__ Cv,
                                                  int Nn, int K,
                                                  long long wOff, long long cOff) {
  const float* Wp = W + (size_t)blockIdx.z * (size_t)wOff;
  __shared__ float Ast[16][68];
  __shared__ float Wst[16][68];
  const int t = threadIdx.x;
  const int row0 = blockIdx.x * 64, col0 = blockIdx.y * 64;
  const int tm = (t & 15) * 4, tn = (t >> 4) * 4;
  const int lr = t >> 2, lk = (t & 3) * 4;
  const int wk = t >> 4, wc = (t & 15) * 4;
  float acc[4][4] = {};
  const float* Arow = A + (size_t)(row0 + lr) * K + lk;
  for (int k0 = 0; k0 < K; k0 += 16) {
    float4 av = *(const float4*)(Arow + k0);
    Ast[lk + 0][lr] = av.x; Ast[lk + 1][lr] = av.y;
    Ast[lk + 2][lr] = av.z; Ast[lk + 3][lr] = av.w;
    *(float4*)&Wst[wk][wc] = *(const float4*)(Wp + (size_t)(k0 + wk) * Nn + col0 + wc);
    __syncthreads();
#pragma unroll
    for (int kk = 0; kk < 16; ++kk) {
      const float4 a = *(const float4*)&Ast[kk][tm];
      const float4 b = *(const float4*)&Wst[kk][tn];
      acc[0][0] = fmaf(a.x, b.x, acc[0][0]); acc[0][1] = fmaf(a.x, b.y, acc[0][1]);
      acc[0][2] = fmaf(a.x, b.z, acc[0][2]); acc[0][3] = fmaf(a.x, b.w, acc[0][3]);
      acc[1][0] = fmaf(a.y, b.x, acc[1][0]); acc[1][1] = fmaf(a.y, b.y, acc[1][1]);
      acc[1][2] = fmaf(a.y, b.z, acc[1][2]); acc[1][3] = fmaf(a.y, b.w, acc[1][3]);
      acc[2][0] = fmaf(a.z, b.x, acc[2][0]); acc[2][1] = fmaf(a.z, b.y, acc[2][1]);
      acc[2][2] = fmaf(a.z, b.z, acc[2][2]); acc[2][3] = fmaf(a.z, b.w, acc[2][3]);
      acc[3][0] = fmaf(a.w, b.x, acc[3][0]); acc[3][1] = fmaf(a.w, b.y, acc[3][1]);
      acc[3][2] = fmaf(a.w, b.z, acc[3][2]); acc[3][3] = fmaf(a.w, b.w, acc[3][3]);
    }
    __syncthreads();
  }
  float bvals[4];
#pragma unroll
  for (int j = 0; j < 4; ++j) bvals[j] = bias ? bias[col0 + tn + j] : 0.f;
#pragma unroll
  for (int i = 0; i < 4; ++i) {
    size_t base = (size_t)blockIdx.z * (size_t)cOff + (size_t)(row0 + tm + i) * Nn + col0 + tn;
    float v[4];
#pragma unroll
    for (int j = 0; j < 4; ++j) {
      float x = acc[i][j] + bvals[j];
      if (RELU) x = fmaxf(x, 0.f);
      v[j] = x;
    }
    if (OUT_BF16) {
      __hip_bfloat16* Cb = (__hip_bfloat16*)Cv;
#pragma unroll
      for (int j = 0; j < 4; ++j) Cb[base + j] = __float2bfloat16(v[j]);
    } else {
      float4 o; o.x = v[0]; o.y = v[1]; o.z = v[2]; o.w = v[3];
      *(float4*)((float*)Cv + base) = o;
    }
  }
}

// ---------------------------------------------------------------------------
// entity_logits = h(bf16) @ w2 + b2.
// ---------------------------------------------------------------------------
__global__ __launch_bounds__(256) void gemm2_k(const __hip_bfloat16* __restrict__ h,
                                               const float* __restrict__ w2,
                                               const float* __restrict__ b2,
                                               float* __restrict__ out) {
  __shared__ float w2s[Ff * Ee];
  __shared__ float b2s[Ee];
  const int t = threadIdx.x;
  for (int i = t; i < Ff * Ee; i += 256) w2s[i] = w2[i];
  if (t < Ee) b2s[t] = b2[t];
  __syncthreads();
  const int lane = t & 63, warp = t >> 6;
  const int row = blockIdx.x * 64 + warp * 16 + (lane >> 2);
  const int q = lane & 3;
  float acc[Ee];
#pragma unroll
  for (int e = 0; e < Ee; ++e) acc[e] = 0.f;
  const unsigned short* hr = (const unsigned short*)h + (size_t)row * Ff;
  for (int k0 = q * 4; k0 < Ff; k0 += 16) {
    ushort4 us = *(const ushort4*)(hr + k0);
    float x0 = __uint_as_float((unsigned)us.x << 16);
    float x1 = __uint_as_float((unsigned)us.y << 16);
    float x2 = __uint_as_float((unsigned)us.z << 16);
    float x3 = __uint_as_float((unsigned)us.w << 16);
#pragma unroll
    for (int e = 0; e < Ee; ++e) {
      acc[e] = fmaf(x0, w2s[(k0 + 0) * Ee + e], acc[e]);
      acc[e] = fmaf(x1, w2s[(k0 + 1) * Ee + e], acc[e]);
      acc[e] = fmaf(x2, w2s[(k0 + 2) * Ee + e], acc[e]);
      acc[e] = fmaf(x3, w2s[(k0 + 3) * Ee + e], acc[e]);
    }
  }
#pragma unroll
  for (int e = 0; e < Ee; ++e) {
    acc[e] += __shfl_xor(acc[e], 1);
    acc[e] += __shfl_xor(acc[e], 2);
  }
  if (q == 0) {
#pragma unroll
    for (int e = 0; e < Ee; ++e) out[(size_t)row * Ee + e] = acc[e] + b2s[e];
  }
}

// ---------------------------------------------------------------------------
// Chunk sums of seq over S (chunks of 16) -> Pc[b][c][h]  (float4 vectorized)
// ---------------------------------------------------------------------------
__global__ __launch_bounds__(192) void chunk_sums(const float* __restrict__ seq,
                                                  float* __restrict__ Pc) {
  const int c = blockIdx.x, b = blockIdx.y;
  const int t = threadIdx.x;   // 192 threads x float4 = 768
  const float4* p = (const float4*)(seq + ((size_t)b * Ss + (size_t)c * CH) * Hh) + t;
  float4 acc = {0.f, 0.f, 0.f, 0.f};
#pragma unroll
  for (int s = 0; s < CH; ++s) {
    float4 v = p[(size_t)s * (Hh / 4)];
    acc.x += v.x; acc.y += v.y; acc.z += v.z; acc.w += v.w;
  }
  ((float4*)(Pc + ((size_t)b * NC + c) * Hh))[t] = acc;
}

// ---------------------------------------------------------------------------
// In-place inclusive scan of Pc along c, per (b,h). Block = (b, 64 h-values).
// LDS 256x64 f32 (64 KB). Wave g scans rows [g*64,(g+1)*64) of its 64 columns,
// then segment offsets are added. 2-way LDS bank aliasing only (free).
// ---------------------------------------------------------------------------
__global__ __launch_bounds__(256) void chunk_scan(float* __restrict__ Pc) {
  __shared__ float tile[NC][64];
  const int b = blockIdx.y;
  const int h0 = blockIdx.x * 64;
  float* base = Pc + (size_t)b * NC * Hh + h0;
  const int l = threadIdx.x & 63, g = threadIdx.x >> 6;
  // coalesced load: wave g loads rows [g*64, g*64+64), 64 consecutive floats/row
#pragma unroll 4
  for (int c = g * 64; c < g * 64 + 64; ++c)
    tile[c][l] = base[(size_t)c * Hh + l];
  __syncthreads();
  // phase 1: per-segment inclusive scan down column l
  float run = 0.f;
#pragma unroll 4
  for (int c = g * 64; c < g * 64 + 64; ++c) {
    run += tile[c][l];
    tile[c][l] = run;
  }
  __syncthreads();
  // phase 2: read earlier-segment totals, then apply after a barrier
  float off = 0.f;
#pragma unroll
  for (int gg = 0; gg < 3; ++gg)
    if (gg < g) off += tile[gg * 64 + 63][l];
  __syncthreads();
  if (g > 0) {
#pragma unroll 4
    for (int c = g * 64; c < g * 64 + 64; ++c)
      tile[c][l] += off;
  }
  __syncthreads();
#pragma unroll 4
  for (int c = g * 64; c < g * 64 + 64; ++c)
    base[(size_t)c * Hh + l] = tile[c][l];
}

// ---------------------------------------------------------------------------
// entity_reprs: O(1) chunk-range via inclusive prefix + <=30 edge rows.
// sum over chunks [cs,ce) = Inc[ce-1] - Inc[cs-1] (Inc[-1]=0).
// ---------------------------------------------------------------------------
__global__ __launch_bounds__(192) void entity_reprs_k(const float* __restrict__ seq,
                                                      const float* __restrict__ Pc,
                                                      const int* __restrict__ spans,
                                                      float* __restrict__ reprs) {
  const int bn = blockIdx.x;
  const int b = bn >> 6;
  const int start = spans[bn * 2], end = spans[bn * 2 + 1];
  const int cnt = max(end - start, 1);
  const float inv = 1.0f / (float)cnt;
  const int cs = (start + CH - 1) >> 4, ce = end >> 4;
  const float* seqb = seq + (size_t)b * Ss * Hh;
  const float4* Pcb = (const float4*)(Pc + (size_t)b * NC * Hh);
  const int t = threadIdx.x;  // 192 x float4 = 768
  float4 acc = {0.f, 0.f, 0.f, 0.f};
  if (cs <= ce) {
    if (cs < ce) {
      float4 hi = Pcb[(size_t)(ce - 1) * 192 + t];
      acc.x += hi.x; acc.y += hi.y; acc.z += hi.z; acc.w += hi.w;
      if (cs > 0) {
        float4 lo = Pcb[(size_t)(cs - 1) * 192 + t];
        acc.x -= lo.x; acc.y -= lo.y; acc.z -= lo.z; acc.w -= lo.w;
      }
    }
    for (int s = start; s < cs * CH; ++s) {
      float4 v = ((const float4*)(seqb + (size_t)s * Hh))[t];
      acc.x += v.x; acc.y += v.y; acc.z += v.z; acc.w += v.w;
    }
    for (int s = ce * CH; s < end; ++s) {
      float4 v = ((const float4*)(seqb + (size_t)s * Hh))[t];
      acc.x += v.x; acc.y += v.y; acc.z += v.z; acc.w += v.w;
    }
  } else {
    for (int s = start; s < end; ++s) {
      float4 v = ((const float4*)(seqb + (size_t)s * Hh))[t];
      acc.x += v.x; acc.y += v.y; acc.z += v.z; acc.w += v.w;
    }
  }
  float4 o; o.x = acc.x * inv; o.y = acc.y * inv; o.z = acc.z * inv; o.w = acc.w * inv;
  ((float4*)(reprs + (size_t)bn * Hh))[t] = o;
}

// ---------------------------------------------------------------------------
// pooled argmax (positive 1/count scaling is argmax-invariant)
// ---------------------------------------------------------------------------
__global__ __launch_bounds__(256) void pooled_argmax(const float* __restrict__ elog,
                                                     const int* __restrict__ spans,
                                                     float* __restrict__ etypes) {
  const int bn = blockIdx.x * 4 + (threadIdx.x >> 6);
  const int lane = threadIdx.x & 63;
  const int b = bn >> 6;
  const int start = spans[bn * 2], end = spans[bn * 2 + 1];
  float acc[Ee];
#pragma unroll
  for (int e = 0; e < Ee; ++e) acc[e] = 0.f;
  const float* p = elog + (size_t)b * Ss * Ee;
  for (int s = start + lane; s < end; s += 64) {
    const float* q = p + (size_t)s * Ee;
#pragma unroll
    for (int e = 0; e < Ee; ++e) acc[e] += q[e];
  }
#pragma unroll
  for (int off = 32; off; off >>= 1)
#pragma unroll
    for (int e = 0; e < Ee; ++e) acc[e] += __shfl_down(acc[e], off);
  if (lane == 0) {
    int best = 0; float bv = acc[0];
#pragma unroll
    for (int e = 1; e < Ee; ++e) if (acc[e] > bv) { bv = acc[e]; best = e; }
    etypes[bn] = (float)best;
  }
}

// ---------------------------------------------------------------------------
// relations: one wave per (b,p); U/V factorization of the concat GEMM.
// ---------------------------------------------------------------------------
__global__ __launch_bounds__(256) void relations_k(const float* __restrict__ UV,
                                                   const float* __restrict__ rb1,
                                                   const float* __restrict__ rw2,
                                                   const float* __restrict__ rb2,
                                                   float* __restrict__ rlogits,
                                                   float* __restrict__ rtypes) {
  const int p = blockIdx.x * 4 + (threadIdx.x >> 6);
  const int lane = threadIdx.x & 63;
  const int b = p / Pp, pp = p % Pp;
  int i = 0, off = 0;
  while (off + (Nn_ENT - 1 - i) <= pp) { off += Nn_ENT - 1 - i; ++i; }
  const int j = i + 1 + (pp - off);
  const float* u = UV + ((size_t)b * Nn_ENT + i) * Hh;
  const float* v = UV + (size_t)512 * Hh + ((size_t)b * Nn_ENT + j) * Hh;
  float acc[Rr];
#pragma unroll
  for (int r = 0; r < Rr; ++r) acc[r] = 0.f;
  for (int k = lane; k < Hh; k += 64) {
    float x = fmaxf(u[k] + v[k] + rb1[k], 0.f);
    const float* w = rw2 + (size_t)k * Rr;
#pragma unroll
    for (int r = 0; r < Rr; ++r) acc[r] = fmaf(x, w[r], acc[r]);
  }
#pragma unroll
  for (int off2 = 32; off2; off2 >>= 1)
#pragma unroll
    for (int r = 0; r < Rr; ++r) acc[r] += __shfl_down(acc[r], off2);
  if (lane == 0) {
    int best = 0; float bv = acc[0] + rb2[0];
    rlogits[(size_t)p * Rr + 0] = bv;
#pragma unroll
    for (int r = 1; r < Rr; ++r) {
      float val = acc[r] + rb2[r];
      rlogits[(size_t)p * Rr + r] = val;
      if (val > bv) { bv = val; best = r; }
    }
    rtypes[p] = (float)best;
  }
}

// ---------------------------------------------------------------------------
extern "C" void kernel_launch(void* const* d_in, const int* in_sizes, int n_in,
                              void* d_out, int out_size, void* d_ws, size_t ws_size,
                              hipStream_t stream) {
  const float* seq   = (const float*)d_in[0];
  const int*   spans = (const int*)d_in[2];
  const float* w1    = (const float*)d_in[3];
  const float* b1    = (const float*)d_in[4];
  const float* w2    = (const float*)d_in[5];
  const float* b2    = (const float*)d_in[6];
  const float* rw1   = (const float*)d_in[7];
  const float* rb1   = (const float*)d_in[8];
  const float* rw2   = (const float*)d_in[9];
  const float* rb2   = (const float*)d_in[10];

  float* out_elog = (float*)d_out;               // (B,S,E)   294912
  float* out_rlog = out_elog + 294912;           // (B,P,R)   161280
  float* out_repr = out_rlog + 161280;           // (B,N,H)   393216
  float* out_etyp = out_repr + 393216;           // (B,N)     512
  float* out_rtyp = out_etyp + 512;              // (B,P)     16128

  // workspace: h (bf16) | Pc (f32) | UV (f32) | Wt (bf16)
  __hip_bfloat16* ws_h  = (__hip_bfloat16*)d_ws;                           // 25165824 B
  float*          ws_pc = (float*)((char*)d_ws + 25165824);                // 6291456 B
  float*          ws_uv = (float*)((char*)d_ws + 25165824 + 6291456);      // 3145728 B
  unsigned short* ws_wt = (unsigned short*)((char*)d_ws + 25165824 + 6291456 + 3145728); // 589824 B

  // 0) w1 -> bf16 transposed
  transpose_w1<<<dim3(12, 6), 256, 0, stream>>>(w1, ws_wt);
  // 1) h = relu(seq @ w1 + b1) via bf16 MFMA
  gemm1_mfma<<<768, 256, 0, stream>>>(seq, ws_wt, b1, (unsigned short*)ws_h);
  // 2) entity_logits = h @ w2 + b2
  gemm2_k<<<512, 256, 0, stream>>>(ws_h, w2, b2, out_elog);
  // 3) chunk sums + parallel prefix scan
  chunk_sums<<<dim3(NC, Bb), 192, 0, stream>>>(seq, ws_pc);
  chunk_scan<<<dim3(Hh / 64, Bb), 256, 0, stream>>>(ws_pc);
  // 4) entity_reprs (prefix diff + edge rows)
  entity_reprs_k<<<512, 192, 0, stream>>>(seq, ws_pc, spans, out_repr);
  // 5) U,V = reprs @ rw1 halves (f32, small)
  gemm_tiled<false, false><<<dim3(8, 12, 2), 256, 0, stream>>>(
      out_repr, rw1, nullptr, (void*)ws_uv, Hh, Hh, (long long)Hh * Hh, (long long)512 * Hh);
  // 6) entity_types via pooled-logits argmax
  pooled_argmax<<<128, 256, 0, stream>>>(out_elog, spans, out_etyp);
  // 7) relation logits + types
  relations_k<<<4032, 256, 0, stream>>>(ws_uv, rb1, rw2, rb2, out_rlog, out_rtyp);
}

// Round 4
// 193.179 us; speedup vs baseline: 2.1000x; 1.0602x over previous
//
#include <hip/hip_runtime.h>
#include <hip/hip_bf16.h>

// Problem constants
#define Hh 768
#define Ff 384      // H/2
#define Ee 9
#define Rr 10
#define Bb 8
#define Ss 4096
#define Nn_ENT 64
#define Pp 2016     // N*(N-1)/2
#define CH 16       // chunk size for seq prefix
#define NC 256      // S/CH

typedef short bf16x8 __attribute__((ext_vector_type(8)));
typedef float f32x4 __attribute__((ext_vector_type(4)));

// ---------------------------------------------------------------------------
// w1 (768x384 f32, k-major) -> Wt (384x768 bf16) via LDS tile transpose
// ---------------------------------------------------------------------------
__global__ __launch_bounds__(256) void transpose_w1(const float* __restrict__ w1,
                                                    unsigned short* __restrict__ wt) {
  __shared__ unsigned short tile[64][65];
  const int bk = blockIdx.x * 64;   // k block (12)
  const int bc = blockIdx.y * 64;   // col block (6)
  const int c = threadIdx.x & 63, kq = threadIdx.x >> 6;
#pragma unroll
  for (int i = 0; i < 16; ++i) {
    int k = kq * 16 + i;
    float v = w1[(size_t)(bk + k) * Ff + bc + c];
    tile[c][k] = __bfloat16_as_ushort(__float2bfloat16(v));
  }
  __syncthreads();
  const int k2 = threadIdx.x & 63, cq = threadIdx.x >> 6;
#pragma unroll
  for (int i = 0; i < 16; ++i) {
    int c2 = cq * 16 + i;
    wt[(size_t)(bc + c2) * Hh + bk + k2] = tile[c2][k2];
  }
}

// ---------------------------------------------------------------------------
// GEMM1: h = relu(seq @ w1 + b1) via bf16 MFMA, fused f32->bf16 staging.
// BM=64 x BN=128 tile, BK=64, 4 waves 2x2 (32x64 each), 16x16x32 MFMA.
// Reg-held prefetch of next K-step (loads overlap MFMA), single LDS buffer,
// XOR-swizzled 16B granules (g ^= row&7) -> conflict-free writes, 2-way reads.
// Grid 1536 = 512 m-tiles x 3 n-tiles, XCD-chunked swizzle.
// ---------------------------------------------------------------------------
__global__ __launch_bounds__(256, 4) void gemm1_mfma(const float* __restrict__ A,
                                                     const unsigned short* __restrict__ Wt,
                                                     const float* __restrict__ b1,
                                                     unsigned short* __restrict__ H) {
  __shared__ short As[64][64];    // 8 KB
  __shared__ short Bs[128][64];   // 16 KB
  const int wg = blockIdx.x;
  const int lin = (wg & 7) * 192 + (wg >> 3);   // 1536 % 8 == 0 -> bijective
  const int mt = lin / 3, nt = lin % 3;
  const int row0 = mt * 64, col0 = nt * 128;
  const int t = threadIdx.x;
  const int wid = t >> 6, lane = t & 63;
  const int wm = wid >> 1, wn = wid & 1;
  const int fr = lane & 15, fq = lane >> 4;

  // staging maps: A row by 4 threads (2 granules each), B row by 2 (4 granules)
  const int ar = t >> 2, ag = (t & 3) * 2;
  const int br = t >> 1, bg = (t & 1) * 4;
  const float* aptr = A + (size_t)(row0 + ar) * Hh + ag * 8;
  const unsigned short* bptr = Wt + (size_t)(col0 + br) * Hh + bg * 8;

  f32x4 acc[2][4] = {};
  float4 pa[4];
  bf16x8 pb[4];

  // prologue: load K-step 0
#pragma unroll
  for (int l = 0; l < 4; ++l) pa[l] = ((const float4*)aptr)[l];
#pragma unroll
  for (int w = 0; w < 4; ++w) pb[w] = ((const bf16x8*)bptr)[w];

#define STAGE() do {                                                          \
    union { bf16x8 v; __hip_bfloat162 h2[4]; } u0, u1;                        \
    u0.h2[0] = __float22bfloat162_rn(float2{pa[0].x, pa[0].y});               \
    u0.h2[1] = __float22bfloat162_rn(float2{pa[0].z, pa[0].w});               \
    u0.h2[2] = __float22bfloat162_rn(float2{pa[1].x, pa[1].y});               \
    u0.h2[3] = __float22bfloat162_rn(float2{pa[1].z, pa[1].w});               \
    u1.h2[0] = __float22bfloat162_rn(float2{pa[2].x, pa[2].y});               \
    u1.h2[1] = __float22bfloat162_rn(float2{pa[2].z, pa[2].w});               \
    u1.h2[2] = __float22bfloat162_rn(float2{pa[3].x, pa[3].y});               \
    u1.h2[3] = __float22bfloat162_rn(float2{pa[3].z, pa[3].w});               \
    *(bf16x8*)&As[ar][((ag + 0) ^ (ar & 7)) * 8] = u0.v;                      \
    *(bf16x8*)&As[ar][((ag + 1) ^ (ar & 7)) * 8] = u1.v;                      \
    _Pragma("unroll")                                                         \
    for (int w = 0; w < 4; ++w)                                               \
      *(bf16x8*)&Bs[br][((bg + w) ^ (br & 7)) * 8] = pb[w];                   \
  } while (0)

  STAGE();
  __syncthreads();

  for (int ks = 0; ; ++ks) {
    const bool more = ks < (Hh / 64) - 1;
    if (more) {
      const float* ap = aptr + (ks + 1) * 64;
      const unsigned short* bp = bptr + (ks + 1) * 64;
#pragma unroll
      for (int l = 0; l < 4; ++l) pa[l] = ((const float4*)ap)[l];
#pragma unroll
      for (int w = 0; w < 4; ++w) pb[w] = ((const bf16x8*)bp)[w];
    }
    // compute current LDS tile
#pragma unroll
    for (int kk = 0; kk < 2; ++kk) {
      const int g2 = ((kk * 4 + fq) ^ (fr & 7)) * 8;
      bf16x8 am[2], bn[4];
#pragma unroll
      for (int m = 0; m < 2; ++m)
        am[m] = *(const bf16x8*)&As[wm * 32 + m * 16 + fr][g2];
#pragma unroll
      for (int n = 0; n < 4; ++n)
        bn[n] = *(const bf16x8*)&Bs[wn * 64 + n * 16 + fr][g2];
#pragma unroll
      for (int m = 0; m < 2; ++m)
#pragma unroll
        for (int n = 0; n < 4; ++n)
          acc[m][n] = __builtin_amdgcn_mfma_f32_16x16x32_bf16(am[m], bn[n], acc[m][n], 0, 0, 0);
    }
    if (!more) break;
    __syncthreads();   // all waves done reading LDS
    STAGE();
    __syncthreads();   // new tile visible
  }
#undef STAGE

  // epilogue: bias + relu, store bf16. C/D: col=lane&15, row=fq*4+reg
#pragma unroll
  for (int n = 0; n < 4; ++n) {
    const int col = col0 + wn * 64 + n * 16 + fr;
    const float bias = b1[col];
#pragma unroll
    for (int m = 0; m < 2; ++m) {
      const int rbase = row0 + wm * 32 + m * 16 + fq * 4;
#pragma unroll
      for (int j = 0; j < 4; ++j) {
        float x = fmaxf(acc[m][n][j] + bias, 0.f);
        H[(size_t)(rbase + j) * Ff + col] = __bfloat16_as_ushort(__float2bfloat16(x));
      }
    }
  }
}

// ---------------------------------------------------------------------------
// Generic 64x64-tile f32 GEMM (kept for the small U/V projection).
// ---------------------------------------------------------------------------
template<bool RELU, bool OUT_BF16>
__global__ __launch_bounds__(256) void gemm_tiled(const float* __restrict__ A,
                                                  const float* __restrict__ W,
                                                  const float* __restrict__ bias,
                                                  void* __restrict__ Cv,
                                                  int Nn, int K,
                                                  long long wOff, long long cOff) {
  const float* Wp = W + (size_t)blockIdx.z * (size_t)wOff;
  __shared__ float Ast[16][68];
  __shared__ float Wst[16][68];
  const int t = threadIdx.x;
  const int row0 = blockIdx.x * 64, col0 = blockIdx.y * 64;
  const int tm = (t & 15) * 4, tn = (t >> 4) * 4;
  const int lr = t >> 2, lk = (t & 3) * 4;
  const int wk = t >> 4, wc = (t & 15) * 4;
  float acc[4][4] = {};
  const float* Arow = A + (size_t)(row0 + lr) * K + lk;
  for (int k0 = 0; k0 < K; k0 += 16) {
    float4 av = *(const float4*)(Arow + k0);
    Ast[lk + 0][lr] = av.x; Ast[lk + 1][lr] = av.y;
    Ast[lk + 2][lr] = av.z; Ast[lk + 3][lr] = av.w;
    *(float4*)&Wst[wk][wc] = *(const float4*)(Wp + (size_t)(k0 + wk) * Nn + col0 + wc);
    __syncthreads();
#pragma unroll
    for (int kk = 0; kk < 16; ++kk) {
      const float4 a = *(const float4*)&Ast[kk][tm];
      const float4 b = *(const float4*)&Wst[kk][tn];
      acc[0][0] = fmaf(a.x, b.x, acc[0][0]); acc[0][1] = fmaf(a.x, b.y, acc[0][1]);
      acc[0][2] = fmaf(a.x, b.z, acc[0][2]); acc[0][3] = fmaf(a.x, b.w, acc[0][3]);
      acc[1][0] = fmaf(a.y, b.x, acc[1][0]); acc[1][1] = fmaf(a.y, b.y, acc[1][1]);
      acc[1][2] = fmaf(a.y, b.z, acc[1][2]); acc[1][3] = fmaf(a.y, b.w, acc[1][3]);
      acc[2][0] = fmaf(a.z, b.x, acc[2][0]); acc[2][1] = fmaf(a.z, b.y, acc[2][1]);
      acc[2][2] = fmaf(a.z, b.z, acc[2][2]); acc[2][3] = fmaf(a.z, b.w, acc[2][3]);
      acc[3][0] = fmaf(a.w, b.x, acc[3][0]); acc[3][1] = fmaf(a.w, b.y, acc[3][1]);
      acc[3][2] = fmaf(a.w, b.z, acc[3][2]); acc[3][3] = fmaf(a.w, b.w, acc[3][3]);
    }
    __syncthreads();
  }
  float bvals[4];
#pragma unroll
  for (int j = 0; j < 4; ++j) bvals[j] = bias ? bias[col0 + tn + j] : 0.f;
#pragma unroll
  for (int i = 0; i < 4; ++i) {
    size_t base = (size_t)blockIdx.z * (size_t)cOff + (size_t)(row0 + tm + i) * Nn + col0 + tn;
    float v[4];
#pragma unroll
    for (int j = 0; j < 4; ++j) {
      float x = acc[i][j] + bvals[j];
      if (RELU) x = fmaxf(x, 0.f);
      v[j] = x;
    }
    if (OUT_BF16) {
      __hip_bfloat16* Cb = (__hip_bfloat16*)Cv;
#pragma unroll
      for (int j = 0; j < 4; ++j) Cb[base + j] = __float2bfloat16(v[j]);
    } else {
      float4 o; o.x = v[0]; o.y = v[1]; o.z = v[2]; o.w = v[3];
      *(float4*)((float*)Cv + base) = o;
    }
  }
}

// ---------------------------------------------------------------------------
// entity_logits = h(bf16) @ w2 + b2.
// ---------------------------------------------------------------------------
__global__ __launch_bounds__(256) void gemm2_k(const __hip_bfloat16* __restrict__ h,
                                               const float* __restrict__ w2,
                                               const float* __restrict__ b2,
                                               float* __restrict__ out) {
  __shared__ float w2s[Ff * Ee];
  __shared__ float b2s[Ee];
  const int t = threadIdx.x;
  for (int i = t; i < Ff * Ee; i += 256) w2s[i] = w2[i];
  if (t < Ee) b2s[t] = b2[t];
  __syncthreads();
  const int lane = t & 63, warp = t >> 6;
  const int row = blockIdx.x * 64 + warp * 16 + (lane >> 2);
  const int q = lane & 3;
  float acc[Ee];
#pragma unroll
  for (int e = 0; e < Ee; ++e) acc[e] = 0.f;
  const unsigned short* hr = (const unsigned short*)h + (size_t)row * Ff;
  for (int k0 = q * 4; k0 < Ff; k0 += 16) {
    ushort4 us = *(const ushort4*)(hr + k0);
    float x0 = __uint_as_float((unsigned)us.x << 16);
    float x1 = __uint_as_float((unsigned)us.y << 16);
    float x2 = __uint_as_float((unsigned)us.z << 16);
    float x3 = __uint_as_float((unsigned)us.w << 16);
#pragma unroll
    for (int e = 0; e < Ee; ++e) {
      acc[e] = fmaf(x0, w2s[(k0 + 0) * Ee + e], acc[e]);
      acc[e] = fmaf(x1, w2s[(k0 + 1) * Ee + e], acc[e]);
      acc[e] = fmaf(x2, w2s[(k0 + 2) * Ee + e], acc[e]);
      acc[e] = fmaf(x3, w2s[(k0 + 3) * Ee + e], acc[e]);
    }
  }
#pragma unroll
  for (int e = 0; e < Ee; ++e) {
    acc[e] += __shfl_xor(acc[e], 1);
    acc[e] += __shfl_xor(acc[e], 2);
  }
  if (q == 0) {
#pragma unroll
    for (int e = 0; e < Ee; ++e) out[(size_t)row * Ee + e] = acc[e] + b2s[e];
  }
}

// ---------------------------------------------------------------------------
// Chunk sums of seq over S (chunks of 16) -> Pc[b][c][h]  (float4 vectorized)
// ---------------------------------------------------------------------------
__global__ __launch_bounds__(192) void chunk_sums(const float* __restrict__ seq,
                                                  float* __restrict__ Pc) {
  const int c = blockIdx.x, b = blockIdx.y;
  const int t = threadIdx.x;   // 192 threads x float4 = 768
  const float4* p = (const float4*)(seq + ((size_t)b * Ss + (size_t)c * CH) * Hh) + t;
  float4 acc = {0.f, 0.f, 0.f, 0.f};
#pragma unroll
  for (int s = 0; s < CH; ++s) {
    float4 v = p[(size_t)s * (Hh / 4)];
    acc.x += v.x; acc.y += v.y; acc.z += v.z; acc.w += v.w;
  }
  ((float4*)(Pc + ((size_t)b * NC + c) * Hh))[t] = acc;
}

// ---------------------------------------------------------------------------
// In-place inclusive scan of Pc along c, per (b,h). Block = (b, 64 h-values).
// ---------------------------------------------------------------------------
__global__ __launch_bounds__(256) void chunk_scan(float* __restrict__ Pc) {
  __shared__ float tile[NC][64];
  const int b = blockIdx.y;
  const int h0 = blockIdx.x * 64;
  float* base = Pc + (size_t)b * NC * Hh + h0;
  const int l = threadIdx.x & 63, g = threadIdx.x >> 6;
#pragma unroll 4
  for (int c = g * 64; c < g * 64 + 64; ++c)
    tile[c][l] = base[(size_t)c * Hh + l];
  __syncthreads();
  float run = 0.f;
#pragma unroll 4
  for (int c = g * 64; c < g * 64 + 64; ++c) {
    run += tile[c][l];
    tile[c][l] = run;
  }
  __syncthreads();
  float off = 0.f;
#pragma unroll
  for (int gg = 0; gg < 3; ++gg)
    if (gg < g) off += tile[gg * 64 + 63][l];
  __syncthreads();
  if (g > 0) {
#pragma unroll 4
    for (int c = g * 64; c < g * 64 + 64; ++c)
      tile[c][l] += off;
  }
  __syncthreads();
#pragma unroll 4
  for (int c = g * 64; c < g * 64 + 64; ++c)
    base[(size_t)c * Hh + l] = tile[c][l];
}

// ---------------------------------------------------------------------------
// entity_reprs: O(1) chunk-range via inclusive prefix + <=30 edge rows.
// ---------------------------------------------------------------------------
__global__ __launch_bounds__(192) void entity_reprs_k(const float* __restrict__ seq,
                                                      const float* __restrict__ Pc,
                                                      const int* __restrict__ spans,
                                                      float* __restrict__ reprs) {
  const int bn = blockIdx.x;
  const int b = bn >> 6;
  const int start = spans[bn * 2], end = spans[bn * 2 + 1];
  const int cnt = max(end - start, 1);
  const float inv = 1.0f / (float)cnt;
  const int cs = (start + CH - 1) >> 4, ce = end >> 4;
  const float* seqb = seq + (size_t)b * Ss * Hh;
  const float4* Pcb = (const float4*)(Pc + (size_t)b * NC * Hh);
  const int t = threadIdx.x;  // 192 x float4 = 768
  float4 acc = {0.f, 0.f, 0.f, 0.f};
  if (cs <= ce) {
    if (cs < ce) {
      float4 hi = Pcb[(size_t)(ce - 1) * 192 + t];
      acc.x += hi.x; acc.y += hi.y; acc.z += hi.z; acc.w += hi.w;
      if (cs > 0) {
        float4 lo = Pcb[(size_t)(cs - 1) * 192 + t];
        acc.x -= lo.x; acc.y -= lo.y; acc.z -= lo.z; acc.w -= lo.w;
      }
    }
    for (int s = start; s < cs * CH; ++s) {
      float4 v = ((const float4*)(seqb + (size_t)s * Hh))[t];
      acc.x += v.x; acc.y += v.y; acc.z += v.z; acc.w += v.w;
    }
    for (int s = ce * CH; s < end; ++s) {
      float4 v = ((const float4*)(seqb + (size_t)s * Hh))[t];
      acc.x += v.x; acc.y += v.y; acc.z += v.z; acc.w += v.w;
    }
  } else {
    for (int s = start; s < end; ++s) {
      float4 v = ((const float4*)(seqb + (size_t)s * Hh))[t];
      acc.x += v.x; acc.y += v.y; acc.z += v.z; acc.w += v.w;
    }
  }
  float4 o; o.x = acc.x * inv; o.y = acc.y * inv; o.z = acc.z * inv; o.w = acc.w * inv;
  ((float4*)(reprs + (size_t)bn * Hh))[t] = o;
}

// ---------------------------------------------------------------------------
// pooled argmax (positive 1/count scaling is argmax-invariant)
// ---------------------------------------------------------------------------
__global__ __launch_bounds__(256) void pooled_argmax(const float* __restrict__ elog,
                                                     const int* __restrict__ spans,
                                                     float* __restrict__ etypes) {
  const int bn = blockIdx.x * 4 + (threadIdx.x >> 6);
  const int lane = threadIdx.x & 63;
  const int b = bn >> 6;
  const int start = spans[bn * 2], end = spans[bn * 2 + 1];
  float acc[Ee];
#pragma unroll
  for (int e = 0; e < Ee; ++e) acc[e] = 0.f;
  const float* p = elog + (size_t)b * Ss * Ee;
  for (int s = start + lane; s < end; s += 64) {
    const float* q = p + (size_t)s * Ee;
#pragma unroll
    for (int e = 0; e < Ee; ++e) acc[e] += q[e];
  }
#pragma unroll
  for (int off = 32; off; off >>= 1)
#pragma unroll
    for (int e = 0; e < Ee; ++e) acc[e] += __shfl_down(acc[e], off);
  if (lane == 0) {
    int best = 0; float bv = acc[0];
#pragma unroll
    for (int e = 1; e < Ee; ++e) if (acc[e] > bv) { bv = acc[e]; best = e; }
    etypes[bn] = (float)best;
  }
}

// ---------------------------------------------------------------------------
// relations: one wave per (b,p); U/V factorization of the concat GEMM.
// ---------------------------------------------------------------------------
__global__ __launch_bounds__(256) void relations_k(const float* __restrict__ UV,
                                                   const float* __restrict__ rb1,
                                                   const float* __restrict__ rw2,
                                                   const float* __restrict__ rb2,
                                                   float* __restrict__ rlogits,
                                                   float* __restrict__ rtypes) {
  const int p = blockIdx.x * 4 + (threadIdx.x >> 6);
  const int lane = threadIdx.x & 63;
  const int b = p / Pp, pp = p % Pp;
  int i = 0, off = 0;
  while (off + (Nn_ENT - 1 - i) <= pp) { off += Nn_ENT - 1 - i; ++i; }
  const int j = i + 1 + (pp - off);
  const float* u = UV + ((size_t)b * Nn_ENT + i) * Hh;
  const float* v = UV + (size_t)512 * Hh + ((size_t)b * Nn_ENT + j) * Hh;
  float acc[Rr];
#pragma unroll
  for (int r = 0; r < Rr; ++r) acc[r] = 0.f;
  for (int k = lane; k < Hh; k += 64) {
    float x = fmaxf(u[k] + v[k] + rb1[k], 0.f);
    const float* w = rw2 + (size_t)k * Rr;
#pragma unroll
    for (int r = 0; r < Rr; ++r) acc[r] = fmaf(x, w[r], acc[r]);
  }
#pragma unroll
  for (int off2 = 32; off2; off2 >>= 1)
#pragma unroll
    for (int r = 0; r < Rr; ++r) acc[r] += __shfl_down(acc[r], off2);
  if (lane == 0) {
    int best = 0; float bv = acc[0] + rb2[0];
    rlogits[(size_t)p * Rr + 0] = bv;
#pragma unroll
    for (int r = 1; r < Rr; ++r) {
      float val = acc[r] + rb2[r];
      rlogits[(size_t)p * Rr + r] = val;
      if (val > bv) { bv = val; best = r; }
    }
    rtypes[p] = (float)best;
  }
}

// ---------------------------------------------------------------------------
extern "C" void kernel_launch(void* const* d_in, const int* in_sizes, int n_in,
                              void* d_out, int out_size, void* d_ws, size_t ws_size,
                              hipStream_t stream) {
  const float* seq   = (const float*)d_in[0];
  const int*   spans = (const int*)d_in[2];
  const float* w1    = (const float*)d_in[3];
  const float* b1    = (const float*)d_in[4];
  const float* w2    = (const float*)d_in[5];
  const float* b2    = (const float*)d_in[6];
  const float* rw1   = (const float*)d_in[7];
  const float* rb1   = (const float*)d_in[8];
  const float* rw2   = (const float*)d_in[9];
  const float* rb2   = (const float*)d_in[10];

  float* out_elog = (float*)d_out;               // (B,S,E)   294912
  float* out_rlog = out_elog + 294912;           // (B,P,R)   161280
  float* out_repr = out_rlog + 161280;           // (B,N,H)   393216
  float* out_etyp = out_repr + 393216;           // (B,N)     512
  float* out_rtyp = out_etyp + 512;              // (B,P)     16128

  // workspace: h (bf16) | Pc (f32) | UV (f32) | Wt (bf16)
  __hip_bfloat16* ws_h  = (__hip_bfloat16*)d_ws;                           // 25165824 B
  float*          ws_pc = (float*)((char*)d_ws + 25165824);                // 6291456 B
  float*          ws_uv = (float*)((char*)d_ws + 25165824 + 6291456);      // 3145728 B
  unsigned short* ws_wt = (unsigned short*)((char*)d_ws + 25165824 + 6291456 + 3145728); // 589824 B

  // 0) w1 -> bf16 transposed
  transpose_w1<<<dim3(12, 6), 256, 0, stream>>>(w1, ws_wt);
  // 1) h = relu(seq @ w1 + b1) via bf16 MFMA (pipelined, 1536 blocks)
  gemm1_mfma<<<1536, 256, 0, stream>>>(seq, ws_wt, b1, (unsigned short*)ws_h);
  // 2) entity_logits = h @ w2 + b2
  gemm2_k<<<512, 256, 0, stream>>>(ws_h, w2, b2, out_elog);
  // 3) chunk sums + parallel prefix scan
  chunk_sums<<<dim3(NC, Bb), 192, 0, stream>>>(seq, ws_pc);
  chunk_scan<<<dim3(Hh / 64, Bb), 256, 0, stream>>>(ws_pc);
  // 4) entity_reprs (prefix diff + edge rows)
  entity_reprs_k<<<512, 192, 0, stream>>>(seq, ws_pc, spans, out_repr);
  // 5) U,V = reprs @ rw1 halves (f32, small)
  gemm_tiled<false, false><<<dim3(8, 12, 2), 256, 0, stream>>>(
      out_repr, rw1, nullptr, (void*)ws_uv, Hh, Hh, (long long)Hh * Hh, (long long)512 * Hh);
  // 6) entity_types via pooled-logits argmax
  pooled_argmax<<<128, 256, 0, stream>>>(out_elog, spans, out_etyp);
  // 7) relation logits + types
  relations_k<<<4032, 256, 0, stream>>>(ws_uv, rb1, rw2, rb2, out_rlog, out_rtyp);
}

// Round 5
// 188.933 us; speedup vs baseline: 2.1471x; 1.0225x over previous
//
#include <hip/hip_runtime.h>
#include <hip/hip_bf16.h>

// Problem constants
#define Hh 768
#define Ff 384      // H/2
#define Ee 9
#define Rr 10
#define Bb 8
#define Ss 4096
#define Nn_ENT 64
#define Pp 2016     // N*(N-1)/2
#define CH 16       // chunk size for seq prefix
#define NC 256      // S/CH

typedef short bf16x8 __attribute__((ext_vector_type(8)));
typedef float f32x4 __attribute__((ext_vector_type(4)));

// async global->LDS, 16B per lane. LDS dest is wave-uniform base + lane*16.
__device__ __forceinline__ void async_copy16(void* lds, const void* g) {
  auto* l = (__attribute__((address_space(3))) unsigned int*)(lds);
  auto* p = (const __attribute__((address_space(1))) unsigned int*)(g);
  __builtin_amdgcn_global_load_lds(p, l, 16, 0, 0);
}

// ---------------------------------------------------------------------------
// w1 (768x384 f32, k-major) -> Wt (384x768 bf16) via LDS tile transpose
// ---------------------------------------------------------------------------
__global__ __launch_bounds__(256) void transpose_w1(const float* __restrict__ w1,
                                                    unsigned short* __restrict__ wt) {
  __shared__ unsigned short tile[64][65];
  const int bk = blockIdx.x * 64;   // k block (12)
  const int bc = blockIdx.y * 64;   // col block (6)
  const int c = threadIdx.x & 63, kq = threadIdx.x >> 6;
#pragma unroll
  for (int i = 0; i < 16; ++i) {
    int k = kq * 16 + i;
    float v = w1[(size_t)(bk + k) * Ff + bc + c];
    tile[c][k] = __bfloat16_as_ushort(__float2bfloat16(v));
  }
  __syncthreads();
  const int k2 = threadIdx.x & 63, cq = threadIdx.x >> 6;
#pragma unroll
  for (int i = 0; i < 16; ++i) {
    int c2 = cq * 16 + i;
    wt[(size_t)(bc + c2) * Hh + bk + k2] = tile[c2][k2];
  }
}

// ---------------------------------------------------------------------------
// seq_prep: one streaming pass over seq. Emits (a) seq16 = bf16(seq) for the
// MFMA GEMM, (b) per-chunk column sums Pc[b][c][h] (chunks of 16 rows).
// Block = one (b, chunk): 192 threads x float4 = 768 h.
// ---------------------------------------------------------------------------
__global__ __launch_bounds__(192) void seq_prep(const float* __restrict__ seq,
                                                unsigned short* __restrict__ seq16,
                                                float* __restrict__ Pc) {
  const int c = blockIdx.x, b = blockIdx.y;
  const int t = threadIdx.x;
  const size_t base = ((size_t)b * Ss + (size_t)c * CH) * Hh;
  const float4* p = (const float4*)(seq + base) + t;
  ushort4* q = (ushort4*)(seq16 + base) + t;
  float4 acc = {0.f, 0.f, 0.f, 0.f};
#pragma unroll
  for (int s = 0; s < CH; ++s) {
    float4 v = p[(size_t)s * (Hh / 4)];
    acc.x += v.x; acc.y += v.y; acc.z += v.z; acc.w += v.w;
    ushort4 o;
    o.x = __bfloat16_as_ushort(__float2bfloat16(v.x));
    o.y = __bfloat16_as_ushort(__float2bfloat16(v.y));
    o.z = __bfloat16_as_ushort(__float2bfloat16(v.z));
    o.w = __bfloat16_as_ushort(__float2bfloat16(v.w));
    q[(size_t)s * (Hh / 4)] = o;
  }
  ((float4*)(Pc + ((size_t)b * NC + c) * Hh))[t] = acc;
}

// ---------------------------------------------------------------------------
// GEMM1: h = relu(seq16 @ Wt^T + b1) via bf16 MFMA. m97 structure:
// 128x128 tile, BK=32, double-buffered LDS (32 KB), global_load_lds width=16,
// one vmcnt-drain + barrier per K-step, next-tile loads issued before compute.
// 4 waves 2x2 (64x64 each), 16x16x32 MFMA, grid 768 XCD-swizzled.
// ---------------------------------------------------------------------------
__global__ __launch_bounds__(256) void gemm1_mfma(const unsigned short* __restrict__ A,
                                                  const unsigned short* __restrict__ Wt,
                                                  const float* __restrict__ b1,
                                                  unsigned short* __restrict__ H) {
  __shared__ unsigned short As[2][128 * 32];   // 8 KB each
  __shared__ unsigned short Bs[2][128 * 32];   // 8 KB each -> 32 KB total
  const int wg = blockIdx.x;
  const int lin = (wg & 7) * 96 + (wg >> 3);   // 768 % 8 == 0 -> bijective
  const int mt = lin / 3, nt = lin % 3;
  const int row0 = mt * 128, col0 = nt * 128;
  const int t = threadIdx.x;
  const int wid = t >> 6, lane = t & 63;
  const int wm = wid >> 1, wn = wid & 1;
  const int fr = lane & 15, fq = lane >> 4;

  // staging map: issue i of wave w covers rows (w*2+i)*16 + (lane>>2),
  // k-offset (lane&3)*8; LDS dest (wave-uniform) elem (w*2+i)*512 + lane*8.
  const int srow = lane >> 2;
  const int skk = (lane & 3) * 8;
  const unsigned short* aA = A + (size_t)row0 * Hh;
  const unsigned short* aB = Wt + (size_t)col0 * Hh;
  const int r0 = wid * 32 + srow;      // issue 0 row
  const int r1 = wid * 32 + 16 + srow; // issue 1 row

#define STAGE(buf, ks) do {                                                   \
    const int k0s = (ks) * 32;                                                \
    async_copy16(&As[buf][(wid * 2 + 0) * 512], aA + (size_t)r0 * Hh + k0s + skk); \
    async_copy16(&As[buf][(wid * 2 + 1) * 512], aA + (size_t)r1 * Hh + k0s + skk); \
    async_copy16(&Bs[buf][(wid * 2 + 0) * 512], aB + (size_t)r0 * Hh + k0s + skk); \
    async_copy16(&Bs[buf][(wid * 2 + 1) * 512], aB + (size_t)r1 * Hh + k0s + skk); \
  } while (0)

  f32x4 acc[4][4] = {};

  STAGE(0, 0);
  __syncthreads();   // drains vmcnt+lgkmcnt, then barrier

  int cur = 0;
  for (int ks = 0; ks < Hh / 32; ++ks) {
    const bool more = ks < (Hh / 32) - 1;
    if (more) STAGE(cur ^ 1, ks + 1);   // loads fly during compute
    bf16x8 af[4], bfr[4];
#pragma unroll
    for (int m = 0; m < 4; ++m)
      af[m] = *(const bf16x8*)&As[cur][(wm * 64 + m * 16 + fr) * 32 + fq * 8];
#pragma unroll
    for (int n = 0; n < 4; ++n)
      bfr[n] = *(const bf16x8*)&Bs[cur][(wn * 64 + n * 16 + fr) * 32 + fq * 8];
#pragma unroll
    for (int m = 0; m < 4; ++m)
#pragma unroll
      for (int n = 0; n < 4; ++n)
        acc[m][n] = __builtin_amdgcn_mfma_f32_16x16x32_bf16(af[m], bfr[n], acc[m][n], 0, 0, 0);
    if (more) {
      __syncthreads();  // drains the in-flight gload_lds; new tile visible
      cur ^= 1;
    }
  }
#undef STAGE

  // epilogue: bias + relu, store bf16. C/D: col=lane&15, row=fq*4+reg
#pragma unroll
  for (int n = 0; n < 4; ++n) {
    const int col = col0 + wn * 64 + n * 16 + fr;
    const float bias = b1[col];
#pragma unroll
    for (int m = 0; m < 4; ++m) {
      const int rbase = row0 + wm * 64 + m * 16 + fq * 4;
#pragma unroll
      for (int j = 0; j < 4; ++j) {
        float x = fmaxf(acc[m][n][j] + bias, 0.f);
        H[(size_t)(rbase + j) * Ff + col] = __bfloat16_as_ushort(__float2bfloat16(x));
      }
    }
  }
}

// ---------------------------------------------------------------------------
// Generic 64x64-tile f32 GEMM (kept for the small U/V projection).
// ---------------------------------------------------------------------------
template<bool RELU, bool OUT_BF16>
__global__ __launch_bounds__(256) void gemm_tiled(const float* __restrict__ A,
                                                  const float* __restrict__ W,
                                                  const float* __restrict__ bias,
                                                  void* __restrict__ Cv,
                                                  int Nn, int K,
                                                  long long wOff, long long cOff) {
  const float* Wp = W + (size_t)blockIdx.z * (size_t)wOff;
  __shared__ float Ast[16][68];
  __shared__ float Wst[16][68];
  const int t = threadIdx.x;
  const int row0 = blockIdx.x * 64, col0 = blockIdx.y * 64;
  const int tm = (t & 15) * 4, tn = (t >> 4) * 4;
  const int lr = t >> 2, lk = (t & 3) * 4;
  const int wk = t >> 4, wc = (t & 15) * 4;
  float acc[4][4] = {};
  const float* Arow = A + (size_t)(row0 + lr) * K + lk;
  for (int k0 = 0; k0 < K; k0 += 16) {
    float4 av = *(const float4*)(Arow + k0);
    Ast[lk + 0][lr] = av.x; Ast[lk + 1][lr] = av.y;
    Ast[lk + 2][lr] = av.z; Ast[lk + 3][lr] = av.w;
    *(float4*)&Wst[wk][wc] = *(const float4*)(Wp + (size_t)(k0 + wk) * Nn + col0 + wc);
    __syncthreads();
#pragma unroll
    for (int kk = 0; kk < 16; ++kk) {
      const float4 a = *(const float4*)&Ast[kk][tm];
      const float4 b = *(const float4*)&Wst[kk][tn];
      acc[0][0] = fmaf(a.x, b.x, acc[0][0]); acc[0][1] = fmaf(a.x, b.y, acc[0][1]);
      acc[0][2] = fmaf(a.x, b.z, acc[0][2]); acc[0][3] = fmaf(a.x, b.w, acc[0][3]);
      acc[1][0] = fmaf(a.y, b.x, acc[1][0]); acc[1][1] = fmaf(a.y, b.y, acc[1][1]);
      acc[1][2] = fmaf(a.y, b.z, acc[1][2]); acc[1][3] = fmaf(a.y, b.w, acc[1][3]);
      acc[2][0] = fmaf(a.z, b.x, acc[2][0]); acc[2][1] = fmaf(a.z, b.y, acc[2][1]);
      acc[2][2] = fmaf(a.z, b.z, acc[2][2]); acc[2][3] = fmaf(a.z, b.w, acc[2][3]);
      acc[3][0] = fmaf(a.w, b.x, acc[3][0]); acc[3][1] = fmaf(a.w, b.y, acc[3][1]);
      acc[3][2] = fmaf(a.w, b.z, acc[3][2]); acc[3][3] = fmaf(a.w, b.w, acc[3][3]);
    }
    __syncthreads();
  }
  float bvals[4];
#pragma unroll
  for (int j = 0; j < 4; ++j) bvals[j] = bias ? bias[col0 + tn + j] : 0.f;
#pragma unroll
  for (int i = 0; i < 4; ++i) {
    size_t base = (size_t)blockIdx.z * (size_t)cOff + (size_t)(row0 + tm + i) * Nn + col0 + tn;
    float v[4];
#pragma unroll
    for (int j = 0; j < 4; ++j) {
      float x = acc[i][j] + bvals[j];
      if (RELU) x = fmaxf(x, 0.f);
      v[j] = x;
    }
    if (OUT_BF16) {
      __hip_bfloat16* Cb = (__hip_bfloat16*)Cv;
#pragma unroll
      for (int j = 0; j < 4; ++j) Cb[base + j] = __float2bfloat16(v[j]);
    } else {
      float4 o; o.x = v[0]; o.y = v[1]; o.z = v[2]; o.w = v[3];
      *(float4*)((float*)Cv + base) = o;
    }
  }
}

// ---------------------------------------------------------------------------
// entity_logits = h(bf16) @ w2 + b2.
// ---------------------------------------------------------------------------
__global__ __launch_bounds__(256) void gemm2_k(const __hip_bfloat16* __restrict__ h,
                                               const float* __restrict__ w2,
                                               const float* __restrict__ b2,
                                               float* __restrict__ out) {
  __shared__ float w2s[Ff * Ee];
  __shared__ float b2s[Ee];
  const int t = threadIdx.x;
  for (int i = t; i < Ff * Ee; i += 256) w2s[i] = w2[i];
  if (t < Ee) b2s[t] = b2[t];
  __syncthreads();
  const int lane = t & 63, warp = t >> 6;
  const int row = blockIdx.x * 64 + warp * 16 + (lane >> 2);
  const int q = lane & 3;
  float acc[Ee];
#pragma unroll
  for (int e = 0; e < Ee; ++e) acc[e] = 0.f;
  const unsigned short* hr = (const unsigned short*)h + (size_t)row * Ff;
  for (int k0 = q * 4; k0 < Ff; k0 += 16) {
    ushort4 us = *(const ushort4*)(hr + k0);
    float x0 = __uint_as_float((unsigned)us.x << 16);
    float x1 = __uint_as_float((unsigned)us.y << 16);
    float x2 = __uint_as_float((unsigned)us.z << 16);
    float x3 = __uint_as_float((unsigned)us.w << 16);
#pragma unroll
    for (int e = 0; e < Ee; ++e) {
      acc[e] = fmaf(x0, w2s[(k0 + 0) * Ee + e], acc[e]);
      acc[e] = fmaf(x1, w2s[(k0 + 1) * Ee + e], acc[e]);
      acc[e] = fmaf(x2, w2s[(k0 + 2) * Ee + e], acc[e]);
      acc[e] = fmaf(x3, w2s[(k0 + 3) * Ee + e], acc[e]);
    }
  }
#pragma unroll
  for (int e = 0; e < Ee; ++e) {
    acc[e] += __shfl_xor(acc[e], 1);
    acc[e] += __shfl_xor(acc[e], 2);
  }
  if (q == 0) {
#pragma unroll
    for (int e = 0; e < Ee; ++e) out[(size_t)row * Ee + e] = acc[e] + b2s[e];
  }
}

// ---------------------------------------------------------------------------
// In-place inclusive scan of Pc along c, per (b,h). Block = (b, 64 h-values).
// ---------------------------------------------------------------------------
__global__ __launch_bounds__(256) void chunk_scan(float* __restrict__ Pc) {
  __shared__ float tile[NC][64];
  const int b = blockIdx.y;
  const int h0 = blockIdx.x * 64;
  float* base = Pc + (size_t)b * NC * Hh + h0;
  const int l = threadIdx.x & 63, g = threadIdx.x >> 6;
#pragma unroll 4
  for (int c = g * 64; c < g * 64 + 64; ++c)
    tile[c][l] = base[(size_t)c * Hh + l];
  __syncthreads();
  float run = 0.f;
#pragma unroll 4
  for (int c = g * 64; c < g * 64 + 64; ++c) {
    run += tile[c][l];
    tile[c][l] = run;
  }
  __syncthreads();
  float off = 0.f;
#pragma unroll
  for (int gg = 0; gg < 3; ++gg)
    if (gg < g) off += tile[gg * 64 + 63][l];
  __syncthreads();
  if (g > 0) {
#pragma unroll 4
    for (int c = g * 64; c < g * 64 + 64; ++c)
      tile[c][l] += off;
  }
  __syncthreads();
#pragma unroll 4
  for (int c = g * 64; c < g * 64 + 64; ++c)
    base[(size_t)c * Hh + l] = tile[c][l];
}

// ---------------------------------------------------------------------------
// entity_reprs: O(1) chunk-range via inclusive prefix + <=30 edge rows.
// ---------------------------------------------------------------------------
__global__ __launch_bounds__(192) void entity_reprs_k(const float* __restrict__ seq,
                                                      const float* __restrict__ Pc,
                                                      const int* __restrict__ spans,
                                                      float* __restrict__ reprs) {
  const int bn = blockIdx.x;
  const int b = bn >> 6;
  const int start = spans[bn * 2], end = spans[bn * 2 + 1];
  const int cnt = max(end - start, 1);
  const float inv = 1.0f / (float)cnt;
  const int cs = (start + CH - 1) >> 4, ce = end >> 4;
  const float* seqb = seq + (size_t)b * Ss * Hh;
  const float4* Pcb = (const float4*)(Pc + (size_t)b * NC * Hh);
  const int t = threadIdx.x;  // 192 x float4 = 768
  float4 acc = {0.f, 0.f, 0.f, 0.f};
  if (cs <= ce) {
    if (cs < ce) {
      float4 hi = Pcb[(size_t)(ce - 1) * 192 + t];
      acc.x += hi.x; acc.y += hi.y; acc.z += hi.z; acc.w += hi.w;
      if (cs > 0) {
        float4 lo = Pcb[(size_t)(cs - 1) * 192 + t];
        acc.x -= lo.x; acc.y -= lo.y; acc.z -= lo.z; acc.w -= lo.w;
      }
    }
    for (int s = start; s < cs * CH; ++s) {
      float4 v = ((const float4*)(seqb + (size_t)s * Hh))[t];
      acc.x += v.x; acc.y += v.y; acc.z += v.z; acc.w += v.w;
    }
    for (int s = ce * CH; s < end; ++s) {
      float4 v = ((const float4*)(seqb + (size_t)s * Hh))[t];
      acc.x += v.x; acc.y += v.y; acc.z += v.z; acc.w += v.w;
    }
  } else {
    for (int s = start; s < end; ++s) {
      float4 v = ((const float4*)(seqb + (size_t)s * Hh))[t];
      acc.x += v.x; acc.y += v.y; acc.z += v.z; acc.w += v.w;
    }
  }
  float4 o; o.x = acc.x * inv; o.y = acc.y * inv; o.z = acc.z * inv; o.w = acc.w * inv;
  ((float4*)(reprs + (size_t)bn * Hh))[t] = o;
}

// ---------------------------------------------------------------------------
// pooled argmax (positive 1/count scaling is argmax-invariant)
// ---------------------------------------------------------------------------
__global__ __launch_bounds__(256) void pooled_argmax(const float* __restrict__ elog,
                                                     const int* __restrict__ spans,
                                                     float* __restrict__ etypes) {
  const int bn = blockIdx.x * 4 + (threadIdx.x >> 6);
  const int lane = threadIdx.x & 63;
  const int b = bn >> 6;
  const int start = spans[bn * 2], end = spans[bn * 2 + 1];
  float acc[Ee];
#pragma unroll
  for (int e = 0; e < Ee; ++e) acc[e] = 0.f;
  const float* p = elog + (size_t)b * Ss * Ee;
  for (int s = start + lane; s < end; s += 64) {
    const float* q = p + (size_t)s * Ee;
#pragma unroll
    for (int e = 0; e < Ee; ++e) acc[e] += q[e];
  }
#pragma unroll
  for (int off = 32; off; off >>= 1)
#pragma unroll
    for (int e = 0; e < Ee; ++e) acc[e] += __shfl_down(acc[e], off);
  if (lane == 0) {
    int best = 0; float bv = acc[0];
#pragma unroll
    for (int e = 1; e < Ee; ++e) if (acc[e] > bv) { bv = acc[e]; best = e; }
    etypes[bn] = (float)best;
  }
}

// ---------------------------------------------------------------------------
// relations: one wave per (b,p); U/V factorization of the concat GEMM.
// ---------------------------------------------------------------------------
__global__ __launch_bounds__(256) void relations_k(const float* __restrict__ UV,
                                                   const float* __restrict__ rb1,
                                                   const float* __restrict__ rw2,
                                                   const float* __restrict__ rb2,
                                                   float* __restrict__ rlogits,
                                                   float* __restrict__ rtypes) {
  const int p = blockIdx.x * 4 + (threadIdx.x >> 6);
  const int lane = threadIdx.x & 63;
  const int b = p / Pp, pp = p % Pp;
  int i = 0, off = 0;
  while (off + (Nn_ENT - 1 - i) <= pp) { off += Nn_ENT - 1 - i; ++i; }
  const int j = i + 1 + (pp - off);
  const float* u = UV + ((size_t)b * Nn_ENT + i) * Hh;
  const float* v = UV + (size_t)512 * Hh + ((size_t)b * Nn_ENT + j) * Hh;
  float acc[Rr];
#pragma unroll
  for (int r = 0; r < Rr; ++r) acc[r] = 0.f;
  for (int k = lane; k < Hh; k += 64) {
    float x = fmaxf(u[k] + v[k] + rb1[k], 0.f);
    const float* w = rw2 + (size_t)k * Rr;
#pragma unroll
    for (int r = 0; r < Rr; ++r) acc[r] = fmaf(x, w[r], acc[r]);
  }
#pragma unroll
  for (int off2 = 32; off2; off2 >>= 1)
#pragma unroll
    for (int r = 0; r < Rr; ++r) acc[r] += __shfl_down(acc[r], off2);
  if (lane == 0) {
    int best = 0; float bv = acc[0] + rb2[0];
    rlogits[(size_t)p * Rr + 0] = bv;
#pragma unroll
    for (int r = 1; r < Rr; ++r) {
      float val = acc[r] + rb2[r];
      rlogits[(size_t)p * Rr + r] = val;
      if (val > bv) { bv = val; best = r; }
    }
    rtypes[p] = (float)best;
  }
}

// ---------------------------------------------------------------------------
extern "C" void kernel_launch(void* const* d_in, const int* in_sizes, int n_in,
                              void* d_out, int out_size, void* d_ws, size_t ws_size,
                              hipStream_t stream) {
  const float* seq   = (const float*)d_in[0];
  const int*   spans = (const int*)d_in[2];
  const float* w1    = (const float*)d_in[3];
  const float* b1    = (const float*)d_in[4];
  const float* w2    = (const float*)d_in[5];
  const float* b2    = (const float*)d_in[6];
  const float* rw1   = (const float*)d_in[7];
  const float* rb1   = (const float*)d_in[8];
  const float* rw2   = (const float*)d_in[9];
  const float* rb2   = (const float*)d_in[10];

  float* out_elog = (float*)d_out;               // (B,S,E)   294912
  float* out_rlog = out_elog + 294912;           // (B,P,R)   161280
  float* out_repr = out_rlog + 161280;           // (B,N,H)   393216
  float* out_etyp = out_repr + 393216;           // (B,N)     512
  float* out_rtyp = out_etyp + 512;              // (B,P)     16128

  // workspace layout (bytes):
  // seq16: 0                       50331648  (32768*768*2)
  // h    : 50331648                25165824  (32768*384*2)
  // Pc   : 75497472                 6291456  (8*256*768*4)
  // UV   : 81788928                 3145728  (2*512*768*4)
  // Wt   : 84934656                  589824  (384*768*2)
  unsigned short* ws_s16 = (unsigned short*)d_ws;
  __hip_bfloat16* ws_h   = (__hip_bfloat16*)((char*)d_ws + 50331648);
  float*          ws_pc  = (float*)((char*)d_ws + 75497472);
  float*          ws_uv  = (float*)((char*)d_ws + 81788928);
  unsigned short* ws_wt  = (unsigned short*)((char*)d_ws + 84934656);

  // 0) w1 -> bf16 transposed
  transpose_w1<<<dim3(12, 6), 256, 0, stream>>>(w1, ws_wt);
  // 1) seq -> bf16 + chunk sums (single streaming pass)
  seq_prep<<<dim3(NC, Bb), 192, 0, stream>>>(seq, ws_s16, ws_pc);
  // 2) h = relu(seq16 @ w1 + b1) via bf16 MFMA (gload_lds dbuf pipeline)
  gemm1_mfma<<<768, 256, 0, stream>>>(ws_s16, ws_wt, b1, (unsigned short*)ws_h);
  // 3) entity_logits = h @ w2 + b2
  gemm2_k<<<512, 256, 0, stream>>>(ws_h, w2, b2, out_elog);
  // 4) prefix scan of chunk sums
  chunk_scan<<<dim3(Hh / 64, Bb), 256, 0, stream>>>(ws_pc);
  // 5) entity_reprs (prefix diff + edge rows)
  entity_reprs_k<<<512, 192, 0, stream>>>(seq, ws_pc, spans, out_repr);
  // 6) U,V = reprs @ rw1 halves (f32, small)
  gemm_tiled<false, false><<<dim3(8, 12, 2), 256, 0, stream>>>(
      out_repr, rw1, nullptr, (void*)ws_uv, Hh, Hh, (long long)Hh * Hh, (long long)512 * Hh);
  // 7) entity_types via pooled-logits argmax
  pooled_argmax<<<128, 256, 0, stream>>>(out_elog, spans, out_etyp);
  // 8) relation logits + types
  relations_k<<<4032, 256, 0, stream>>>(ws_uv, rb1, rw2, rb2, out_rlog, out_rtyp);
}

// Round 6
// 168.989 us; speedup vs baseline: 2.4006x; 1.1180x over previous
//
#include <hip/hip_runtime.h>
#include <hip/hip_bf16.h>

// Problem constants
#define Hh 768
#define Ff 384      // H/2
#define Ee 9
#define Rr 10
#define Bb 8
#define Ss 4096
#define Nn_ENT 64
#define Pp 2016     // N*(N-1)/2
#define CH 16       // chunk size for seq prefix
#define NC 256      // S/CH

typedef short bf16x8 __attribute__((ext_vector_type(8)));
typedef float f32x4 __attribute__((ext_vector_type(4)));

// async global->LDS, 16B per lane. LDS dest is wave-uniform base + lane*16.
__device__ __forceinline__ void async_copy16(void* lds, const void* g) {
  auto* l = (__attribute__((address_space(3))) unsigned int*)(lds);
  auto* p = (const __attribute__((address_space(1))) unsigned int*)(g);
  __builtin_amdgcn_global_load_lds(p, l, 16, 0, 0);
}

// ---------------------------------------------------------------------------
// w1 (768x384 f32, k-major) -> Wt (384x768 bf16) via LDS tile transpose
// ---------------------------------------------------------------------------
__global__ __launch_bounds__(256) void transpose_w1(const float* __restrict__ w1,
                                                    unsigned short* __restrict__ wt) {
  __shared__ unsigned short tile[64][65];
  const int bk = blockIdx.x * 64;   // k block (12)
  const int bc = blockIdx.y * 64;   // col block (6)
  const int c = threadIdx.x & 63, kq = threadIdx.x >> 6;
#pragma unroll
  for (int i = 0; i < 16; ++i) {
    int k = kq * 16 + i;
    float v = w1[(size_t)(bk + k) * Ff + bc + c];
    tile[c][k] = __bfloat16_as_ushort(__float2bfloat16(v));
  }
  __syncthreads();
  const int k2 = threadIdx.x & 63, cq = threadIdx.x >> 6;
#pragma unroll
  for (int i = 0; i < 16; ++i) {
    int c2 = cq * 16 + i;
    wt[(size_t)(bc + c2) * Hh + bk + k2] = tile[c2][k2];
  }
}

// ---------------------------------------------------------------------------
// seq_prep: one streaming pass over seq -> seq16 (bf16) + chunk sums Pc.
// ---------------------------------------------------------------------------
__global__ __launch_bounds__(192) void seq_prep(const float* __restrict__ seq,
                                                unsigned short* __restrict__ seq16,
                                                float* __restrict__ Pc) {
  const int c = blockIdx.x, b = blockIdx.y;
  const int t = threadIdx.x;
  const size_t base = ((size_t)b * Ss + (size_t)c * CH) * Hh;
  const float4* p = (const float4*)(seq + base) + t;
  ushort4* q = (ushort4*)(seq16 + base) + t;
  float4 acc = {0.f, 0.f, 0.f, 0.f};
#pragma unroll
  for (int s = 0; s < CH; ++s) {
    float4 v = p[(size_t)s * (Hh / 4)];
    acc.x += v.x; acc.y += v.y; acc.z += v.z; acc.w += v.w;
    ushort4 o;
    o.x = __bfloat16_as_ushort(__float2bfloat16(v.x));
    o.y = __bfloat16_as_ushort(__float2bfloat16(v.y));
    o.z = __bfloat16_as_ushort(__float2bfloat16(v.z));
    o.w = __bfloat16_as_ushort(__float2bfloat16(v.w));
    q[(size_t)s * (Hh / 4)] = o;
  }
  ((float4*)(Pc + ((size_t)b * NC + c) * Hh))[t] = acc;
}

// ---------------------------------------------------------------------------
// GEMM1: h = relu(seq16 @ Wt^T + b1), bf16 MFMA, m97-exact structure:
// 128x128 tile, BK=64, SINGLE 32KB LDS buffer, global_load_lds width=16,
// 2 barriers per K-step (32 MFMA/wave between), TLP from 3 blocks/CU.
// ---------------------------------------------------------------------------
__global__ __launch_bounds__(256) void gemm1_mfma(const unsigned short* __restrict__ A,
                                                  const unsigned short* __restrict__ Wt,
                                                  const float* __restrict__ b1,
                                                  unsigned short* __restrict__ H) {
  __shared__ unsigned short As[128 * 64];   // 16 KB
  __shared__ unsigned short Bs[128 * 64];   // 16 KB
  const int wg = blockIdx.x;
  const int lin = (wg & 7) * 96 + (wg >> 3);   // 768 % 8 == 0 -> bijective
  const int mt = lin / 3, nt = lin % 3;
  const int row0 = mt * 128, col0 = nt * 128;
  const int t = threadIdx.x;
  const int wid = t >> 6, lane = t & 63;
  const int wm = wid >> 1, wn = wid & 1;
  const int fr = lane & 15, fq = lane >> 4;
  // staging: issue i of wave w covers rows (w*4+i)*8 + (lane>>3), cols (lane&7)*8
  const int srow = lane >> 3, scol = (lane & 7) * 8;
  const unsigned short* aA = A + (size_t)row0 * Hh;
  const unsigned short* aB = Wt + (size_t)col0 * Hh;

  f32x4 acc[4][4] = {};

  for (int ks = 0; ks < Hh / 64; ++ks) {
    const int k0 = ks * 64;
#pragma unroll
    for (int i = 0; i < 4; ++i) {
      const int r = (wid * 4 + i) * 8 + srow;
      async_copy16(&As[(wid * 4 + i) * 512], aA + (size_t)r * Hh + k0 + scol);
      async_copy16(&Bs[(wid * 4 + i) * 512], aB + (size_t)r * Hh + k0 + scol);
    }
    __syncthreads();   // drains vmcnt; tile visible
#pragma unroll
    for (int kk = 0; kk < 2; ++kk) {
      bf16x8 af[4], bfr[4];
#pragma unroll
      for (int m = 0; m < 4; ++m)
        af[m] = *(const bf16x8*)&As[(wm * 64 + m * 16 + fr) * 64 + kk * 32 + fq * 8];
#pragma unroll
      for (int n = 0; n < 4; ++n)
        bfr[n] = *(const bf16x8*)&Bs[(wn * 64 + n * 16 + fr) * 64 + kk * 32 + fq * 8];
#pragma unroll
      for (int m = 0; m < 4; ++m)
#pragma unroll
        for (int n = 0; n < 4; ++n)
          acc[m][n] = __builtin_amdgcn_mfma_f32_16x16x32_bf16(af[m], bfr[n], acc[m][n], 0, 0, 0);
    }
    if (ks < Hh / 64 - 1) __syncthreads();   // reads done before next stage
  }

  // epilogue: bias + relu, store bf16. C/D: col=lane&15, row=fq*4+reg
#pragma unroll
  for (int n = 0; n < 4; ++n) {
    const int col = col0 + wn * 64 + n * 16 + fr;
    const float bias = b1[col];
#pragma unroll
    for (int m = 0; m < 4; ++m) {
      const int rbase = row0 + wm * 64 + m * 16 + fq * 4;
#pragma unroll
      for (int j = 0; j < 4; ++j) {
        float x = fmaxf(acc[m][n][j] + bias, 0.f);
        H[(size_t)(rbase + j) * Ff + col] = __bfloat16_as_ushort(__float2bfloat16(x));
      }
    }
  }
}

// ---------------------------------------------------------------------------
// U/V projection, split-K f32: part[ks][uv] += reprs(512x768) @ rw1-half.
// Grid (8,12,8): z = (ks<<1)|uv. Each block: 64x64 tile, K-chunk 192.
// ---------------------------------------------------------------------------
__global__ __launch_bounds__(256) void gemm_uv_splitk(const float* __restrict__ A,
                                                      const float* __restrict__ rw1,
                                                      float* __restrict__ part) {
  const int uv = blockIdx.z & 1, ks = blockIdx.z >> 1;
  const float* Wp = rw1 + (size_t)uv * Hh * Hh + (size_t)ks * 192 * Hh;
  __shared__ float Ast[16][68];
  __shared__ float Wst[16][68];
  const int t = threadIdx.x;
  const int row0 = blockIdx.x * 64, col0 = blockIdx.y * 64;
  const int tm = (t & 15) * 4, tn = (t >> 4) * 4;
  const int lr = t >> 2, lk = (t & 3) * 4;
  const int wk = t >> 4, wc = (t & 15) * 4;
  float acc[4][4] = {};
  const float* Arow = A + (size_t)(row0 + lr) * Hh + ks * 192 + lk;
  for (int k0 = 0; k0 < 192; k0 += 16) {
    float4 av = *(const float4*)(Arow + k0);
    Ast[lk + 0][lr] = av.x; Ast[lk + 1][lr] = av.y;
    Ast[lk + 2][lr] = av.z; Ast[lk + 3][lr] = av.w;
    *(float4*)&Wst[wk][wc] = *(const float4*)(Wp + (size_t)(k0 + wk) * Hh + col0 + wc);
    __syncthreads();
#pragma unroll
    for (int kk = 0; kk < 16; ++kk) {
      const float4 a = *(const float4*)&Ast[kk][tm];
      const float4 b = *(const float4*)&Wst[kk][tn];
      acc[0][0] = fmaf(a.x, b.x, acc[0][0]); acc[0][1] = fmaf(a.x, b.y, acc[0][1]);
      acc[0][2] = fmaf(a.x, b.z, acc[0][2]); acc[0][3] = fmaf(a.x, b.w, acc[0][3]);
      acc[1][0] = fmaf(a.y, b.x, acc[1][0]); acc[1][1] = fmaf(a.y, b.y, acc[1][1]);
      acc[1][2] = fmaf(a.y, b.z, acc[1][2]); acc[1][3] = fmaf(a.y, b.w, acc[1][3]);
      acc[2][0] = fmaf(a.z, b.x, acc[2][0]); acc[2][1] = fmaf(a.z, b.y, acc[2][1]);
      acc[2][2] = fmaf(a.z, b.z, acc[2][2]); acc[2][3] = fmaf(a.z, b.w, acc[2][3]);
      acc[3][0] = fmaf(a.w, b.x, acc[3][0]); acc[3][1] = fmaf(a.w, b.y, acc[3][1]);
      acc[3][2] = fmaf(a.w, b.z, acc[3][2]); acc[3][3] = fmaf(a.w, b.w, acc[3][3]);
    }
    __syncthreads();
  }
  float* out = part + ((size_t)ks * 2 + uv) * (512 * Hh);
#pragma unroll
  for (int i = 0; i < 4; ++i) {
    float4 o; o.x = acc[i][0]; o.y = acc[i][1]; o.z = acc[i][2]; o.w = acc[i][3];
    *(float4*)(out + (size_t)(row0 + tm + i) * Hh + col0 + tn) = o;
  }
}

// UV[i] = sum of 4 K-split partials
__global__ __launch_bounds__(256) void uv_reduce(const float* __restrict__ part,
                                                 float* __restrict__ uv) {
  const int i = blockIdx.x * 256 + threadIdx.x;   // float4 idx, 196608 total
  const float4* p = (const float4*)part;
  float4 a = p[i], b = p[i + 196608], c = p[i + 2 * 196608], d = p[i + 3 * 196608];
  float4 o;
  o.x = (a.x + b.x) + (c.x + d.x);
  o.y = (a.y + b.y) + (c.y + d.y);
  o.z = (a.z + b.z) + (c.z + d.z);
  o.w = (a.w + b.w) + (c.w + d.w);
  ((float4*)uv)[i] = o;
}

// ---------------------------------------------------------------------------
// entity_logits = h(bf16) @ w2 + b2.
// ---------------------------------------------------------------------------
__global__ __launch_bounds__(256) void gemm2_k(const __hip_bfloat16* __restrict__ h,
                                               const float* __restrict__ w2,
                                               const float* __restrict__ b2,
                                               float* __restrict__ out) {
  __shared__ float w2s[Ff * Ee];
  __shared__ float b2s[Ee];
  const int t = threadIdx.x;
  for (int i = t; i < Ff * Ee; i += 256) w2s[i] = w2[i];
  if (t < Ee) b2s[t] = b2[t];
  __syncthreads();
  const int lane = t & 63, warp = t >> 6;
  const int row = blockIdx.x * 64 + warp * 16 + (lane >> 2);
  const int q = lane & 3;
  float acc[Ee];
#pragma unroll
  for (int e = 0; e < Ee; ++e) acc[e] = 0.f;
  const unsigned short* hr = (const unsigned short*)h + (size_t)row * Ff;
  for (int k0 = q * 4; k0 < Ff; k0 += 16) {
    ushort4 us = *(const ushort4*)(hr + k0);
    float x0 = __uint_as_float((unsigned)us.x << 16);
    float x1 = __uint_as_float((unsigned)us.y << 16);
    float x2 = __uint_as_float((unsigned)us.z << 16);
    float x3 = __uint_as_float((unsigned)us.w << 16);
#pragma unroll
    for (int e = 0; e < Ee; ++e) {
      acc[e] = fmaf(x0, w2s[(k0 + 0) * Ee + e], acc[e]);
      acc[e] = fmaf(x1, w2s[(k0 + 1) * Ee + e], acc[e]);
      acc[e] = fmaf(x2, w2s[(k0 + 2) * Ee + e], acc[e]);
      acc[e] = fmaf(x3, w2s[(k0 + 3) * Ee + e], acc[e]);
    }
  }
#pragma unroll
  for (int e = 0; e < Ee; ++e) {
    acc[e] += __shfl_xor(acc[e], 1);
    acc[e] += __shfl_xor(acc[e], 2);
  }
  if (q == 0) {
#pragma unroll
    for (int e = 0; e < Ee; ++e) out[(size_t)row * Ee + e] = acc[e] + b2s[e];
  }
}

// ---------------------------------------------------------------------------
// In-place inclusive scan of Pc along c, per (b,h). Block = (b, 64 h-values).
// ---------------------------------------------------------------------------
__global__ __launch_bounds__(256) void chunk_scan(float* __restrict__ Pc) {
  __shared__ float tile[NC][64];
  const int b = blockIdx.y;
  const int h0 = blockIdx.x * 64;
  float* base = Pc + (size_t)b * NC * Hh + h0;
  const int l = threadIdx.x & 63, g = threadIdx.x >> 6;
#pragma unroll 4
  for (int c = g * 64; c < g * 64 + 64; ++c)
    tile[c][l] = base[(size_t)c * Hh + l];
  __syncthreads();
  float run = 0.f;
#pragma unroll 4
  for (int c = g * 64; c < g * 64 + 64; ++c) {
    run += tile[c][l];
    tile[c][l] = run;
  }
  __syncthreads();
  float off = 0.f;
#pragma unroll
  for (int gg = 0; gg < 3; ++gg)
    if (gg < g) off += tile[gg * 64 + 63][l];
  __syncthreads();
  if (g > 0) {
#pragma unroll 4
    for (int c = g * 64; c < g * 64 + 64; ++c)
      tile[c][l] += off;
  }
  __syncthreads();
#pragma unroll 4
  for (int c = g * 64; c < g * 64 + 64; ++c)
    base[(size_t)c * Hh + l] = tile[c][l];
}

// ---------------------------------------------------------------------------
// entity_reprs: O(1) chunk-range via inclusive prefix + <=30 edge rows.
// ---------------------------------------------------------------------------
__global__ __launch_bounds__(192) void entity_reprs_k(const float* __restrict__ seq,
                                                      const float* __restrict__ Pc,
                                                      const int* __restrict__ spans,
                                                      float* __restrict__ reprs) {
  const int bn = blockIdx.x;
  const int b = bn >> 6;
  const int start = spans[bn * 2], end = spans[bn * 2 + 1];
  const int cnt = max(end - start, 1);
  const float inv = 1.0f / (float)cnt;
  const int cs = (start + CH - 1) >> 4, ce = end >> 4;
  const float* seqb = seq + (size_t)b * Ss * Hh;
  const float4* Pcb = (const float4*)(Pc + (size_t)b * NC * Hh);
  const int t = threadIdx.x;  // 192 x float4 = 768
  float4 acc = {0.f, 0.f, 0.f, 0.f};
  if (cs <= ce) {
    if (cs < ce) {
      float4 hi = Pcb[(size_t)(ce - 1) * 192 + t];
      acc.x += hi.x; acc.y += hi.y; acc.z += hi.z; acc.w += hi.w;
      if (cs > 0) {
        float4 lo = Pcb[(size_t)(cs - 1) * 192 + t];
        acc.x -= lo.x; acc.y -= lo.y; acc.z -= lo.z; acc.w -= lo.w;
      }
    }
    for (int s = start; s < cs * CH; ++s) {
      float4 v = ((const float4*)(seqb + (size_t)s * Hh))[t];
      acc.x += v.x; acc.y += v.y; acc.z += v.z; acc.w += v.w;
    }
    for (int s = ce * CH; s < end; ++s) {
      float4 v = ((const float4*)(seqb + (size_t)s * Hh))[t];
      acc.x += v.x; acc.y += v.y; acc.z += v.z; acc.w += v.w;
    }
  } else {
    for (int s = start; s < end; ++s) {
      float4 v = ((const float4*)(seqb + (size_t)s * Hh))[t];
      acc.x += v.x; acc.y += v.y; acc.z += v.z; acc.w += v.w;
    }
  }
  float4 o; o.x = acc.x * inv; o.y = acc.y * inv; o.z = acc.z * inv; o.w = acc.w * inv;
  ((float4*)(reprs + (size_t)bn * Hh))[t] = o;
}

// ---------------------------------------------------------------------------
// pooled argmax: one block per entity (512 blocks, 4 waves).
// ---------------------------------------------------------------------------
__global__ __launch_bounds__(256) void pooled_argmax(const float* __restrict__ elog,
                                                     const int* __restrict__ spans,
                                                     float* __restrict__ etypes) {
  __shared__ float red[4][Ee];
  const int bn = blockIdx.x;
  const int b = bn >> 6;
  const int start = spans[bn * 2], end = spans[bn * 2 + 1];
  const int t = threadIdx.x, lane = t & 63, w = t >> 6;
  float acc[Ee];
#pragma unroll
  for (int e = 0; e < Ee; ++e) acc[e] = 0.f;
  const float* p = elog + (size_t)b * Ss * Ee;
  for (int s = start + t; s < end; s += 256) {
    const float* q = p + (size_t)s * Ee;
#pragma unroll
    for (int e = 0; e < Ee; ++e) acc[e] += q[e];
  }
#pragma unroll
  for (int off = 32; off; off >>= 1)
#pragma unroll
    for (int e = 0; e < Ee; ++e) acc[e] += __shfl_down(acc[e], off);
  if (lane == 0) {
#pragma unroll
    for (int e = 0; e < Ee; ++e) red[w][e] = acc[e];
  }
  __syncthreads();
  if (t == 0) {
    int best = 0; float bv = -1e30f;
#pragma unroll
    for (int e = 0; e < Ee; ++e) {
      float v = red[0][e] + red[1][e] + red[2][e] + red[3][e];
      if (v > bv) { bv = v; best = e; }
    }
    etypes[bn] = (float)best;
  }
}

// ---------------------------------------------------------------------------
// relations: one wave per (b,p); U/V factorization of the concat GEMM.
// ---------------------------------------------------------------------------
__global__ __launch_bounds__(256) void relations_k(const float* __restrict__ UV,
                                                   const float* __restrict__ rb1,
                                                   const float* __restrict__ rw2,
                                                   const float* __restrict__ rb2,
                                                   float* __restrict__ rlogits,
                                                   float* __restrict__ rtypes) {
  const int p = blockIdx.x * 4 + (threadIdx.x >> 6);
  const int lane = threadIdx.x & 63;
  const int b = p / Pp, pp = p % Pp;
  int i = 0, off = 0;
  while (off + (Nn_ENT - 1 - i) <= pp) { off += Nn_ENT - 1 - i; ++i; }
  const int j = i + 1 + (pp - off);
  const float* u = UV + ((size_t)b * Nn_ENT + i) * Hh;
  const float* v = UV + (size_t)512 * Hh + ((size_t)b * Nn_ENT + j) * Hh;
  float acc[Rr];
#pragma unroll
  for (int r = 0; r < Rr; ++r) acc[r] = 0.f;
  for (int k = lane; k < Hh; k += 64) {
    float x = fmaxf(u[k] + v[k] + rb1[k], 0.f);
    const float* w = rw2 + (size_t)k * Rr;
#pragma unroll
    for (int r = 0; r < Rr; ++r) acc[r] = fmaf(x, w[r], acc[r]);
  }
#pragma unroll
  for (int off2 = 32; off2; off2 >>= 1)
#pragma unroll
    for (int r = 0; r < Rr; ++r) acc[r] += __shfl_down(acc[r], off2);
  if (lane == 0) {
    int best = 0; float bv = acc[0] + rb2[0];
    rlogits[(size_t)p * Rr + 0] = bv;
#pragma unroll
    for (int r = 1; r < Rr; ++r) {
      float val = acc[r] + rb2[r];
      rlogits[(size_t)p * Rr + r] = val;
      if (val > bv) { bv = val; best = r; }
    }
    rtypes[p] = (float)best;
  }
}

// ---------------------------------------------------------------------------
extern "C" void kernel_launch(void* const* d_in, const int* in_sizes, int n_in,
                              void* d_out, int out_size, void* d_ws, size_t ws_size,
                              hipStream_t stream) {
  const float* seq   = (const float*)d_in[0];
  const int*   spans = (const int*)d_in[2];
  const float* w1    = (const float*)d_in[3];
  const float* b1    = (const float*)d_in[4];
  const float* w2    = (const float*)d_in[5];
  const float* b2    = (const float*)d_in[6];
  const float* rw1   = (const float*)d_in[7];
  const float* rb1   = (const float*)d_in[8];
  const float* rw2   = (const float*)d_in[9];
  const float* rb2   = (const float*)d_in[10];

  float* out_elog = (float*)d_out;               // (B,S,E)   294912
  float* out_rlog = out_elog + 294912;           // (B,P,R)   161280
  float* out_repr = out_rlog + 161280;           // (B,N,H)   393216
  float* out_etyp = out_repr + 393216;           // (B,N)     512
  float* out_rtyp = out_etyp + 512;              // (B,P)     16128

  // workspace layout (bytes):
  unsigned short* ws_s16 = (unsigned short*)d_ws;                         // 50331648
  __hip_bfloat16* ws_h   = (__hip_bfloat16*)((char*)d_ws + 50331648);     // 25165824
  float*          ws_pc  = (float*)((char*)d_ws + 75497472);              //  6291456
  float*          ws_uv  = (float*)((char*)d_ws + 81788928);              //  3145728
  unsigned short* ws_wt  = (unsigned short*)((char*)d_ws + 84934656);     //   589824
  float*          ws_uvp = (float*)((char*)d_ws + 85524480);              // 12582912

  // 0) w1 -> bf16 transposed
  transpose_w1<<<dim3(12, 6), 256, 0, stream>>>(w1, ws_wt);
  // 1) seq -> bf16 + chunk sums (single streaming pass)
  seq_prep<<<dim3(NC, Bb), 192, 0, stream>>>(seq, ws_s16, ws_pc);
  // 2) h = relu(seq16 @ w1 + b1) via bf16 MFMA (m97 structure)
  gemm1_mfma<<<768, 256, 0, stream>>>(ws_s16, ws_wt, b1, (unsigned short*)ws_h);
  // 3) entity_logits = h @ w2 + b2
  gemm2_k<<<512, 256, 0, stream>>>(ws_h, w2, b2, out_elog);
  // 4) prefix scan of chunk sums
  chunk_scan<<<dim3(Hh / 64, Bb), 256, 0, stream>>>(ws_pc);
  // 5) entity_reprs (prefix diff + edge rows)
  entity_reprs_k<<<512, 192, 0, stream>>>(seq, ws_pc, spans, out_repr);
  // 6) U,V = reprs @ rw1 halves: split-K (4) + reduce
  gemm_uv_splitk<<<dim3(8, 12, 8), 256, 0, stream>>>(out_repr, rw1, ws_uvp);
  uv_reduce<<<768, 256, 0, stream>>>(ws_uvp, ws_uv);
  // 7) entity_types via pooled-logits argmax
  pooled_argmax<<<512, 256, 0, stream>>>(out_elog, spans, out_etyp);
  // 8) relation logits + types
  relations_k<<<4032, 256, 0, stream>>>(ws_uv, rb1, rw2, rb2, out_rlog, out_rtyp);
}

// Round 7
// 164.503 us; speedup vs baseline: 2.4660x; 1.0273x over previous
//
#include <hip/hip_runtime.h>
#include <hip/hip_bf16.h>

// Problem constants
#define Hh 768
#define Ff 384      // H/2
#define Ee 9
#define Rr 10
#define Bb 8
#define Ss 4096
#define Nn_ENT 64
#define Pp 2016     // N*(N-1)/2
#define CH 16       // chunk size for seq prefix
#define NC 256      // S/CH

typedef short bf16x8 __attribute__((ext_vector_type(8)));
typedef float f32x4 __attribute__((ext_vector_type(4)));

// async global->LDS, 16B per lane. LDS dest is wave-uniform base + lane*16.
__device__ __forceinline__ void async_copy16(void* lds, const void* g) {
  auto* l = (__attribute__((address_space(3))) unsigned int*)(lds);
  auto* p = (const __attribute__((address_space(1))) unsigned int*)(g);
  __builtin_amdgcn_global_load_lds(p, l, 16, 0, 0);
}

// ---------------------------------------------------------------------------
// w1 (768x384 f32, k-major) -> Wt (384x768 bf16) via LDS tile transpose
// ---------------------------------------------------------------------------
__global__ __launch_bounds__(256) void transpose_w1(const float* __restrict__ w1,
                                                    unsigned short* __restrict__ wt) {
  __shared__ unsigned short tile[64][65];
  const int bk = blockIdx.x * 64;   // k block (12)
  const int bc = blockIdx.y * 64;   // col block (6)
  const int c = threadIdx.x & 63, kq = threadIdx.x >> 6;
#pragma unroll
  for (int i = 0; i < 16; ++i) {
    int k = kq * 16 + i;
    float v = w1[(size_t)(bk + k) * Ff + bc + c];
    tile[c][k] = __bfloat16_as_ushort(__float2bfloat16(v));
  }
  __syncthreads();
  const int k2 = threadIdx.x & 63, cq = threadIdx.x >> 6;
#pragma unroll
  for (int i = 0; i < 16; ++i) {
    int c2 = cq * 16 + i;
    wt[(size_t)(bc + c2) * Hh + bk + k2] = tile[c2][k2];
  }
}

// ---------------------------------------------------------------------------
// seq_prep: one streaming pass over seq -> seq16 (bf16) + chunk sums Pc.
// ---------------------------------------------------------------------------
__global__ __launch_bounds__(192) void seq_prep(const float* __restrict__ seq,
                                                unsigned short* __restrict__ seq16,
                                                float* __restrict__ Pc) {
  const int c = blockIdx.x, b = blockIdx.y;
  const int t = threadIdx.x;
  const size_t base = ((size_t)b * Ss + (size_t)c * CH) * Hh;
  const float4* p = (const float4*)(seq + base) + t;
  ushort4* q = (ushort4*)(seq16 + base) + t;
  float4 acc = {0.f, 0.f, 0.f, 0.f};
#pragma unroll
  for (int s = 0; s < CH; ++s) {
    float4 v = p[(size_t)s * (Hh / 4)];
    acc.x += v.x; acc.y += v.y; acc.z += v.z; acc.w += v.w;
    ushort4 o;
    o.x = __bfloat16_as_ushort(__float2bfloat16(v.x));
    o.y = __bfloat16_as_ushort(__float2bfloat16(v.y));
    o.z = __bfloat16_as_ushort(__float2bfloat16(v.z));
    o.w = __bfloat16_as_ushort(__float2bfloat16(v.w));
    q[(size_t)s * (Hh / 4)] = o;
  }
  ((float4*)(Pc + ((size_t)b * NC + c) * Hh))[t] = acc;
}

// ---------------------------------------------------------------------------
// GEMM1+GEMM2 fused: elog = relu(seq16 @ Wt^T + b1) @ w2 + b2.
// BM=64 x BN=384 (full width), BK=64, 512 threads / 8 waves (2m x 4n),
// wave tile 32x96 (acc 2x6 f32x4). gload_lds staging, 2-barrier K-loop.
// Epilogue: h stays in registers; per-lane dot with LDS w2 + shfl reduce +
// cross-wave LDS reduce (aliases dead A/B tile). h is NEVER materialized.
// ---------------------------------------------------------------------------
__global__ __launch_bounds__(512, 4) void gemm1_fused(const unsigned short* __restrict__ A,
                                                      const unsigned short* __restrict__ Wt,
                                                      const float* __restrict__ b1,
                                                      const float* __restrict__ w2,
                                                      const float* __restrict__ b2,
                                                      float* __restrict__ elog) {
  __shared__ unsigned short AB[(64 + 384) * 64];   // As | Bs = 57344 B
  __shared__ float w2s[Ff * Ee];                   // 13824 B
  __shared__ float b1s[Ff];                        // 1536 B
  __shared__ float b2s[Ee];
  unsigned short* As = AB;
  unsigned short* Bs = AB + 64 * 64;
  float* red = (float*)AB;                         // epilogue alias (9216 B)

  const int t = threadIdx.x;
  const int wid = t >> 6, lane = t & 63;
  const int wm = wid >> 2, wn = wid & 3;
  const int fr = lane & 15, fq = lane >> 4;
  const int row0 = blockIdx.x * 64;

  // cache params in LDS
  for (int i = t; i < Ff * Ee; i += 512) w2s[i] = w2[i];
  for (int i = t; i < Ff; i += 512) b1s[i] = b1[i];
  if (t < Ee) b2s[t] = b2[t];

  // staging maps: thread t covers row t>>3 (0..63), k-granule (t&7)*8
  const unsigned short* aA = A + (size_t)(row0 + (t >> 3)) * Hh + (t & 7) * 8;
  const unsigned short* aB = Wt + (size_t)(t >> 3) * Hh + (t & 7) * 8;

  f32x4 acc[2][6] = {};

  for (int ks = 0; ks < Hh / 64; ++ks) {
    const int k0 = ks * 64;
    async_copy16(&As[wid * 512], aA + k0);
#pragma unroll
    for (int i = 0; i < 6; ++i)
      async_copy16(&Bs[i * 4096 + wid * 512], aB + (size_t)i * 64 * Hh + k0);
    __syncthreads();   // drains vmcnt; tile visible
#pragma unroll
    for (int kk = 0; kk < 2; ++kk) {
      bf16x8 af[2], bfr[6];
#pragma unroll
      for (int m = 0; m < 2; ++m)
        af[m] = *(const bf16x8*)&As[(wm * 32 + m * 16 + fr) * 64 + kk * 32 + fq * 8];
#pragma unroll
      for (int n = 0; n < 6; ++n)
        bfr[n] = *(const bf16x8*)&Bs[(wn * 96 + n * 16 + fr) * 64 + kk * 32 + fq * 8];
#pragma unroll
      for (int m = 0; m < 2; ++m)
#pragma unroll
        for (int n = 0; n < 6; ++n)
          acc[m][n] = __builtin_amdgcn_mfma_f32_16x16x32_bf16(af[m], bfr[n], acc[m][n], 0, 0, 0);
    }
    __syncthreads();   // reads done; safe to restage / alias
  }

  // ---- fused entity-logits epilogue (h in registers) ----
  // C/D layout: col = fr, row = fq*4 + j (within each 16x16 tile).
#pragma unroll
  for (int m = 0; m < 2; ++m) {
#pragma unroll
    for (int j = 0; j < 4; ++j) {
      float p[Ee];
#pragma unroll
      for (int e = 0; e < Ee; ++e) p[e] = 0.f;
#pragma unroll
      for (int n = 0; n < 6; ++n) {
        const int col = wn * 96 + n * 16 + fr;
        const float hv = fmaxf(acc[m][n][j] + b1s[col], 0.f);
        const float* wrow = &w2s[col * Ee];
#pragma unroll
        for (int e = 0; e < Ee; ++e) p[e] = fmaf(hv, wrow[e], p[e]);
      }
      // reduce across the 16 fr-lanes (col dimension)
#pragma unroll
      for (int mask = 1; mask <= 8; mask <<= 1)
#pragma unroll
        for (int e = 0; e < Ee; ++e) p[e] += __shfl_xor(p[e], mask);
      if (fr < Ee) {
        const int row = wm * 32 + m * 16 + fq * 4 + j;
        red[(wn * 64 + row) * Ee + fr] = p[fr];
      }
    }
  }
  __syncthreads();
  // sum the 4 wn partials + bias, write elog
  for (int idx = t; idx < 64 * Ee; idx += 512) {
    const int row = idx / Ee, e = idx - row * Ee;
    float v = red[(0 * 64 + row) * Ee + e] + red[(1 * 64 + row) * Ee + e]
            + red[(2 * 64 + row) * Ee + e] + red[(3 * 64 + row) * Ee + e] + b2s[e];
    elog[(size_t)(row0 + row) * Ee + e] = v;
  }
}

// ---------------------------------------------------------------------------
// U/V projection, split-K f32: part[ks][uv] += reprs(512x768) @ rw1-half.
// Grid (8,12,8): z = (ks<<1)|uv. Each block: 64x64 tile, K-chunk 192.
// ---------------------------------------------------------------------------
__global__ __launch_bounds__(256) void gemm_uv_splitk(const float* __restrict__ A,
                                                      const float* __restrict__ rw1,
                                                      float* __restrict__ part) {
  const int uv = blockIdx.z & 1, ks = blockIdx.z >> 1;
  const float* Wp = rw1 + (size_t)uv * Hh * Hh + (size_t)ks * 192 * Hh;
  __shared__ float Ast[16][68];
  __shared__ float Wst[16][68];
  const int t = threadIdx.x;
  const int row0 = blockIdx.x * 64, col0 = blockIdx.y * 64;
  const int tm = (t & 15) * 4, tn = (t >> 4) * 4;
  const int lr = t >> 2, lk = (t & 3) * 4;
  const int wk = t >> 4, wc = (t & 15) * 4;
  float acc[4][4] = {};
  const float* Arow = A + (size_t)(row0 + lr) * Hh + ks * 192 + lk;
  for (int k0 = 0; k0 < 192; k0 += 16) {
    float4 av = *(const float4*)(Arow + k0);
    Ast[lk + 0][lr] = av.x; Ast[lk + 1][lr] = av.y;
    Ast[lk + 2][lr] = av.z; Ast[lk + 3][lr] = av.w;
    *(float4*)&Wst[wk][wc] = *(const float4*)(Wp + (size_t)(k0 + wk) * Hh + col0 + wc);
    __syncthreads();
#pragma unroll
    for (int kk = 0; kk < 16; ++kk) {
      const float4 a = *(const float4*)&Ast[kk][tm];
      const float4 b = *(const float4*)&Wst[kk][tn];
      acc[0][0] = fmaf(a.x, b.x, acc[0][0]); acc[0][1] = fmaf(a.x, b.y, acc[0][1]);
      acc[0][2] = fmaf(a.x, b.z, acc[0][2]); acc[0][3] = fmaf(a.x, b.w, acc[0][3]);
      acc[1][0] = fmaf(a.y, b.x, acc[1][0]); acc[1][1] = fmaf(a.y, b.y, acc[1][1]);
      acc[1][2] = fmaf(a.y, b.z, acc[1][2]); acc[1][3] = fmaf(a.y, b.w, acc[1][3]);
      acc[2][0] = fmaf(a.z, b.x, acc[2][0]); acc[2][1] = fmaf(a.z, b.y, acc[2][1]);
      acc[2][2] = fmaf(a.z, b.z, acc[2][2]); acc[2][3] = fmaf(a.z, b.w, acc[2][3]);
      acc[3][0] = fmaf(a.w, b.x, acc[3][0]); acc[3][1] = fmaf(a.w, b.y, acc[3][1]);
      acc[3][2] = fmaf(a.w, b.z, acc[3][2]); acc[3][3] = fmaf(a.w, b.w, acc[3][3]);
    }
    __syncthreads();
  }
  float* out = part + ((size_t)ks * 2 + uv) * (512 * Hh);
#pragma unroll
  for (int i = 0; i < 4; ++i) {
    float4 o; o.x = acc[i][0]; o.y = acc[i][1]; o.z = acc[i][2]; o.w = acc[i][3];
    *(float4*)(out + (size_t)(row0 + tm + i) * Hh + col0 + tn) = o;
  }
}

// UV[i] = sum of 4 K-split partials
__global__ __launch_bounds__(256) void uv_reduce(const float* __restrict__ part,
                                                 float* __restrict__ uv) {
  const int i = blockIdx.x * 256 + threadIdx.x;   // float4 idx, 196608 total
  const float4* p = (const float4*)part;
  float4 a = p[i], b = p[i + 196608], c = p[i + 2 * 196608], d = p[i + 3 * 196608];
  float4 o;
  o.x = (a.x + b.x) + (c.x + d.x);
  o.y = (a.y + b.y) + (c.y + d.y);
  o.z = (a.z + b.z) + (c.z + d.z);
  o.w = (a.w + b.w) + (c.w + d.w);
  ((float4*)uv)[i] = o;
}

// ---------------------------------------------------------------------------
// In-place inclusive scan of Pc along c, per (b,h). Block = (b, 64 h-values).
// ---------------------------------------------------------------------------
__global__ __launch_bounds__(256) void chunk_scan(float* __restrict__ Pc) {
  __shared__ float tile[NC][64];
  const int b = blockIdx.y;
  const int h0 = blockIdx.x * 64;
  float* base = Pc + (size_t)b * NC * Hh + h0;
  const int l = threadIdx.x & 63, g = threadIdx.x >> 6;
#pragma unroll 4
  for (int c = g * 64; c < g * 64 + 64; ++c)
    tile[c][l] = base[(size_t)c * Hh + l];
  __syncthreads();
  float run = 0.f;
#pragma unroll 4
  for (int c = g * 64; c < g * 64 + 64; ++c) {
    run += tile[c][l];
    tile[c][l] = run;
  }
  __syncthreads();
  float off = 0.f;
#pragma unroll
  for (int gg = 0; gg < 3; ++gg)
    if (gg < g) off += tile[gg * 64 + 63][l];
  __syncthreads();
  if (g > 0) {
#pragma unroll 4
    for (int c = g * 64; c < g * 64 + 64; ++c)
      tile[c][l] += off;
  }
  __syncthreads();
#pragma unroll 4
  for (int c = g * 64; c < g * 64 + 64; ++c)
    base[(size_t)c * Hh + l] = tile[c][l];
}

// ---------------------------------------------------------------------------
// entity_reprs: O(1) chunk-range via inclusive prefix + <=30 edge rows.
// ---------------------------------------------------------------------------
__global__ __launch_bounds__(192) void entity_reprs_k(const float* __restrict__ seq,
                                                      const float* __restrict__ Pc,
                                                      const int* __restrict__ spans,
                                                      float* __restrict__ reprs) {
  const int bn = blockIdx.x;
  const int b = bn >> 6;
  const int start = spans[bn * 2], end = spans[bn * 2 + 1];
  const int cnt = max(end - start, 1);
  const float inv = 1.0f / (float)cnt;
  const int cs = (start + CH - 1) >> 4, ce = end >> 4;
  const float* seqb = seq + (size_t)b * Ss * Hh;
  const float4* Pcb = (const float4*)(Pc + (size_t)b * NC * Hh);
  const int t = threadIdx.x;  // 192 x float4 = 768
  float4 acc = {0.f, 0.f, 0.f, 0.f};
  if (cs <= ce) {
    if (cs < ce) {
      float4 hi = Pcb[(size_t)(ce - 1) * 192 + t];
      acc.x += hi.x; acc.y += hi.y; acc.z += hi.z; acc.w += hi.w;
      if (cs > 0) {
        float4 lo = Pcb[(size_t)(cs - 1) * 192 + t];
        acc.x -= lo.x; acc.y -= lo.y; acc.z -= lo.z; acc.w -= lo.w;
      }
    }
    for (int s = start; s < cs * CH; ++s) {
      float4 v = ((const float4*)(seqb + (size_t)s * Hh))[t];
      acc.x += v.x; acc.y += v.y; acc.z += v.z; acc.w += v.w;
    }
    for (int s = ce * CH; s < end; ++s) {
      float4 v = ((const float4*)(seqb + (size_t)s * Hh))[t];
      acc.x += v.x; acc.y += v.y; acc.z += v.z; acc.w += v.w;
    }
  } else {
    for (int s = start; s < end; ++s) {
      float4 v = ((const float4*)(seqb + (size_t)s * Hh))[t];
      acc.x += v.x; acc.y += v.y; acc.z += v.z; acc.w += v.w;
    }
  }
  float4 o; o.x = acc.x * inv; o.y = acc.y * inv; o.z = acc.z * inv; o.w = acc.w * inv;
  ((float4*)(reprs + (size_t)bn * Hh))[t] = o;
}

// ---------------------------------------------------------------------------
// pooled argmax: one block per entity (512 blocks, 4 waves).
// ---------------------------------------------------------------------------
__global__ __launch_bounds__(256) void pooled_argmax(const float* __restrict__ elog,
                                                     const int* __restrict__ spans,
                                                     float* __restrict__ etypes) {
  __shared__ float red[4][Ee];
  const int bn = blockIdx.x;
  const int b = bn >> 6;
  const int start = spans[bn * 2], end = spans[bn * 2 + 1];
  const int t = threadIdx.x, lane = t & 63, w = t >> 6;
  float acc[Ee];
#pragma unroll
  for (int e = 0; e < Ee; ++e) acc[e] = 0.f;
  const float* p = elog + (size_t)b * Ss * Ee;
  for (int s = start + t; s < end; s += 256) {
    const float* q = p + (size_t)s * Ee;
#pragma unroll
    for (int e = 0; e < Ee; ++e) acc[e] += q[e];
  }
#pragma unroll
  for (int off = 32; off; off >>= 1)
#pragma unroll
    for (int e = 0; e < Ee; ++e) acc[e] += __shfl_down(acc[e], off);
  if (lane == 0) {
#pragma unroll
    for (int e = 0; e < Ee; ++e) red[w][e] = acc[e];
  }
  __syncthreads();
  if (t == 0) {
    int best = 0; float bv = -1e30f;
#pragma unroll
    for (int e = 0; e < Ee; ++e) {
      float v = red[0][e] + red[1][e] + red[2][e] + red[3][e];
      if (v > bv) { bv = v; best = e; }
    }
    etypes[bn] = (float)best;
  }
}

// ---------------------------------------------------------------------------
// relations: one wave per (b,p); U/V factorization of the concat GEMM.
// ---------------------------------------------------------------------------
__global__ __launch_bounds__(256) void relations_k(const float* __restrict__ UV,
                                                   const float* __restrict__ rb1,
                                                   const float* __restrict__ rw2,
                                                   const float* __restrict__ rb2,
                                                   float* __restrict__ rlogits,
                                                   float* __restrict__ rtypes) {
  const int p = blockIdx.x * 4 + (threadIdx.x >> 6);
  const int lane = threadIdx.x & 63;
  const int b = p / Pp, pp = p % Pp;
  int i = 0, off = 0;
  while (off + (Nn_ENT - 1 - i) <= pp) { off += Nn_ENT - 1 - i; ++i; }
  const int j = i + 1 + (pp - off);
  const float* u = UV + ((size_t)b * Nn_ENT + i) * Hh;
  const float* v = UV + (size_t)512 * Hh + ((size_t)b * Nn_ENT + j) * Hh;
  float acc[Rr];
#pragma unroll
  for (int r = 0; r < Rr; ++r) acc[r] = 0.f;
  for (int k = lane; k < Hh; k += 64) {
    float x = fmaxf(u[k] + v[k] + rb1[k], 0.f);
    const float* w = rw2 + (size_t)k * Rr;
#pragma unroll
    for (int r = 0; r < Rr; ++r) acc[r] = fmaf(x, w[r], acc[r]);
  }
#pragma unroll
  for (int off2 = 32; off2; off2 >>= 1)
#pragma unroll
    for (int r = 0; r < Rr; ++r) acc[r] += __shfl_down(acc[r], off2);
  if (lane == 0) {
    int best = 0; float bv = acc[0] + rb2[0];
    rlogits[(size_t)p * Rr + 0] = bv;
#pragma unroll
    for (int r = 1; r < Rr; ++r) {
      float val = acc[r] + rb2[r];
      rlogits[(size_t)p * Rr + r] = val;
      if (val > bv) { bv = val; best = r; }
    }
    rtypes[p] = (float)best;
  }
}

// ---------------------------------------------------------------------------
extern "C" void kernel_launch(void* const* d_in, const int* in_sizes, int n_in,
                              void* d_out, int out_size, void* d_ws, size_t ws_size,
                              hipStream_t stream) {
  const float* seq   = (const float*)d_in[0];
  const int*   spans = (const int*)d_in[2];
  const float* w1    = (const float*)d_in[3];
  const float* b1    = (const float*)d_in[4];
  const float* w2    = (const float*)d_in[5];
  const float* b2    = (const float*)d_in[6];
  const float* rw1   = (const float*)d_in[7];
  const float* rb1   = (const float*)d_in[8];
  const float* rw2   = (const float*)d_in[9];
  const float* rb2   = (const float*)d_in[10];

  float* out_elog = (float*)d_out;               // (B,S,E)   294912
  float* out_rlog = out_elog + 294912;           // (B,P,R)   161280
  float* out_repr = out_rlog + 161280;           // (B,N,H)   393216
  float* out_etyp = out_repr + 393216;           // (B,N)     512
  float* out_rtyp = out_etyp + 512;              // (B,P)     16128

  // workspace layout (bytes):
  unsigned short* ws_s16 = (unsigned short*)d_ws;                         // 50331648
  float*          ws_pc  = (float*)((char*)d_ws + 50331648);              //  6291456
  float*          ws_uv  = (float*)((char*)d_ws + 56623104);              //  3145728
  unsigned short* ws_wt  = (unsigned short*)((char*)d_ws + 59768832);     //   589824
  float*          ws_uvp = (float*)((char*)d_ws + 60358656);              // 12582912

  // 0) w1 -> bf16 transposed
  transpose_w1<<<dim3(12, 6), 256, 0, stream>>>(w1, ws_wt);
  // 1) seq -> bf16 + chunk sums (single streaming pass)
  seq_prep<<<dim3(NC, Bb), 192, 0, stream>>>(seq, ws_s16, ws_pc);
  // 2) elog = relu(seq16 @ w1 + b1) @ w2 + b2  (fused, h never materialized)
  gemm1_fused<<<512, 512, 0, stream>>>(ws_s16, ws_wt, b1, w2, b2, out_elog);
  // 3) prefix scan of chunk sums
  chunk_scan<<<dim3(Hh / 64, Bb), 256, 0, stream>>>(ws_pc);
  // 4) entity_reprs (prefix diff + edge rows)
  entity_reprs_k<<<512, 192, 0, stream>>>(seq, ws_pc, spans, out_repr);
  // 5) U,V = reprs @ rw1 halves: split-K (4) + reduce
  gemm_uv_splitk<<<dim3(8, 12, 8), 256, 0, stream>>>(out_repr, rw1, ws_uvp);
  uv_reduce<<<768, 256, 0, stream>>>(ws_uvp, ws_uv);
  // 6) entity_types via pooled-logits argmax
  pooled_argmax<<<512, 256, 0, stream>>>(out_elog, spans, out_etyp);
  // 7) relation logits + types
  relations_k<<<4032, 256, 0, stream>>>(ws_uv, rb1, rw2, rb2, out_rlog, out_rtyp);
}

// Round 8
// 162.576 us; speedup vs baseline: 2.4952x; 1.0119x over previous
//
#include <hip/hip_runtime.h>
#include <hip/hip_bf16.h>

// Problem constants
#define Hh 768
#define Ff 384      // H/2
#define Ee 9
#define Rr 10
#define Bb 8
#define Ss 4096
#define Nn_ENT 64
#define Pp 2016     // N*(N-1)/2
#define CH 16       // chunk size for seq prefix
#define NC 256      // S/CH

typedef short bf16x8 __attribute__((ext_vector_type(8)));
typedef float f32x4 __attribute__((ext_vector_type(4)));

// async global->LDS, 16B per lane. LDS dest is wave-uniform base + lane*16.
__device__ __forceinline__ void async_copy16(void* lds, const void* g) {
  auto* l = (__attribute__((address_space(3))) unsigned int*)(lds);
  auto* p = (const __attribute__((address_space(1))) unsigned int*)(g);
  __builtin_amdgcn_global_load_lds(p, l, 16, 0, 0);
}

// ---------------------------------------------------------------------------
// w1 (768x384 f32, k-major) -> Wt (384x768 bf16) via LDS tile transpose
// ---------------------------------------------------------------------------
__global__ __launch_bounds__(256) void transpose_w1(const float* __restrict__ w1,
                                                    unsigned short* __restrict__ wt) {
  __shared__ unsigned short tile[64][65];
  const int bk = blockIdx.x * 64;   // k block (12)
  const int bc = blockIdx.y * 64;   // col block (6)
  const int c = threadIdx.x & 63, kq = threadIdx.x >> 6;
#pragma unroll
  for (int i = 0; i < 16; ++i) {
    int k = kq * 16 + i;
    float v = w1[(size_t)(bk + k) * Ff + bc + c];
    tile[c][k] = __bfloat16_as_ushort(__float2bfloat16(v));
  }
  __syncthreads();
  const int k2 = threadIdx.x & 63, cq = threadIdx.x >> 6;
#pragma unroll
  for (int i = 0; i < 16; ++i) {
    int c2 = cq * 16 + i;
    wt[(size_t)(bc + c2) * Hh + bk + k2] = tile[c2][k2];
  }
}

// ---------------------------------------------------------------------------
// seq_prep: one streaming pass over seq -> seq16 (bf16) + chunk sums Pc.
// ---------------------------------------------------------------------------
__global__ __launch_bounds__(192) void seq_prep(const float* __restrict__ seq,
                                                unsigned short* __restrict__ seq16,
                                                float* __restrict__ Pc) {
  const int c = blockIdx.x, b = blockIdx.y;
  const int t = threadIdx.x;
  const size_t base = ((size_t)b * Ss + (size_t)c * CH) * Hh;
  const float4* p = (const float4*)(seq + base) + t;
  ushort4* q = (ushort4*)(seq16 + base) + t;
  float4 acc = {0.f, 0.f, 0.f, 0.f};
#pragma unroll
  for (int s = 0; s < CH; ++s) {
    float4 v = p[(size_t)s * (Hh / 4)];
    acc.x += v.x; acc.y += v.y; acc.z += v.z; acc.w += v.w;
    ushort4 o;
    o.x = __bfloat16_as_ushort(__float2bfloat16(v.x));
    o.y = __bfloat16_as_ushort(__float2bfloat16(v.y));
    o.z = __bfloat16_as_ushort(__float2bfloat16(v.z));
    o.w = __bfloat16_as_ushort(__float2bfloat16(v.w));
    q[(size_t)s * (Hh / 4)] = o;
  }
  ((float4*)(Pc + ((size_t)b * NC + c) * Hh))[t] = acc;
}

// ---------------------------------------------------------------------------
// GEMM1+GEMM2 fused: elog = relu(seq16 @ Wt^T + b1) @ w2 + b2.
// BM=64 x BN=384 (full width), BK=64, 512 threads / 8 waves (2m x 4n).
// T2 swizzle via PRE-SWIZZLED GLOBAL SOURCE (LDS dest linear, required by
// global_load_lds) + same-XOR on ds_read: granule g of row r lives in LDS
// slot g^(r&7). Read lanes then land 2-way per bank (free) instead of 16-way.
// ---------------------------------------------------------------------------
__global__ __launch_bounds__(512, 4) void gemm1_fused(const unsigned short* __restrict__ A,
                                                      const unsigned short* __restrict__ Wt,
                                                      const float* __restrict__ b1,
                                                      const float* __restrict__ w2,
                                                      const float* __restrict__ b2,
                                                      float* __restrict__ elog) {
  __shared__ unsigned short AB[(64 + 384) * 64];   // As | Bs = 57344 B
  __shared__ float w2s[Ff * Ee];                   // 13824 B
  __shared__ float b1s[Ff];                        // 1536 B
  __shared__ float b2s[Ee];
  unsigned short* As = AB;
  unsigned short* Bs = AB + 64 * 64;
  float* red = (float*)AB;                         // epilogue alias (9216 B)

  const int t = threadIdx.x;
  const int wid = t >> 6, lane = t & 63;
  const int wm = wid >> 2, wn = wid & 3;
  const int fr = lane & 15, fq = lane >> 4;
  const int row0 = blockIdx.x * 64;

  // cache params in LDS
  for (int i = t; i < Ff * Ee; i += 512) w2s[i] = w2[i];
  for (int i = t; i < Ff; i += 512) b1s[i] = b1[i];
  if (t < Ee) b2s[t] = b2[t];

  // staging maps: thread t covers row t>>3, SOURCE granule (t&7)^((t>>3)&7).
  // LDS stays linear -> LDS[row][g] holds global granule g^(row&7).
  const int sg = (t & 7) ^ ((t >> 3) & 7);
  const unsigned short* aA = A + (size_t)(row0 + (t >> 3)) * Hh + sg * 8;
  const unsigned short* aB = Wt + (size_t)(t >> 3) * Hh + sg * 8;

  f32x4 acc[2][6] = {};

  for (int ks = 0; ks < Hh / 64; ++ks) {
    const int k0 = ks * 64;
    async_copy16(&As[wid * 512], aA + k0);
#pragma unroll
    for (int i = 0; i < 6; ++i)
      async_copy16(&Bs[i * 4096 + wid * 512], aB + (size_t)i * 64 * Hh + k0);
    __syncthreads();   // drains vmcnt; tile visible
#pragma unroll
    for (int kk = 0; kk < 2; ++kk) {
      // granule kk*4+fq of row r -> LDS slot (kk*4+fq)^(r&7); r&7 == fr&7 here
      const int g2 = ((kk * 4 + fq) ^ (fr & 7)) * 8;
      bf16x8 af[2], bfr[6];
#pragma unroll
      for (int m = 0; m < 2; ++m)
        af[m] = *(const bf16x8*)&As[(wm * 32 + m * 16 + fr) * 64 + g2];
#pragma unroll
      for (int n = 0; n < 6; ++n)
        bfr[n] = *(const bf16x8*)&Bs[(wn * 96 + n * 16 + fr) * 64 + g2];
#pragma unroll
      for (int m = 0; m < 2; ++m)
#pragma unroll
        for (int n = 0; n < 6; ++n)
          acc[m][n] = __builtin_amdgcn_mfma_f32_16x16x32_bf16(af[m], bfr[n], acc[m][n], 0, 0, 0);
    }
    __syncthreads();   // reads done; safe to restage / alias
  }

  // ---- fused entity-logits epilogue (h in registers) ----
#pragma unroll
  for (int m = 0; m < 2; ++m) {
#pragma unroll
    for (int j = 0; j < 4; ++j) {
      float p[Ee];
#pragma unroll
      for (int e = 0; e < Ee; ++e) p[e] = 0.f;
#pragma unroll
      for (int n = 0; n < 6; ++n) {
        const int col = wn * 96 + n * 16 + fr;
        const float hv = fmaxf(acc[m][n][j] + b1s[col], 0.f);
        const float* wrow = &w2s[col * Ee];
#pragma unroll
        for (int e = 0; e < Ee; ++e) p[e] = fmaf(hv, wrow[e], p[e]);
      }
#pragma unroll
      for (int mask = 1; mask <= 8; mask <<= 1)
#pragma unroll
        for (int e = 0; e < Ee; ++e) p[e] += __shfl_xor(p[e], mask);
      if (fr < Ee) {
        const int row = wm * 32 + m * 16 + fq * 4 + j;
        red[(wn * 64 + row) * Ee + fr] = p[fr];
      }
    }
  }
  __syncthreads();
  for (int idx = t; idx < 64 * Ee; idx += 512) {
    const int row = idx / Ee, e = idx - row * Ee;
    float v = red[(0 * 64 + row) * Ee + e] + red[(1 * 64 + row) * Ee + e]
            + red[(2 * 64 + row) * Ee + e] + red[(3 * 64 + row) * Ee + e] + b2s[e];
    elog[(size_t)(row0 + row) * Ee + e] = v;
  }
}

// ---------------------------------------------------------------------------
// U/V projection, split-K f32: part[ks][uv] += reprs(512x768) @ rw1-half.
// ---------------------------------------------------------------------------
__global__ __launch_bounds__(256) void gemm_uv_splitk(const float* __restrict__ A,
                                                      const float* __restrict__ rw1,
                                                      float* __restrict__ part) {
  const int uv = blockIdx.z & 1, ks = blockIdx.z >> 1;
  const float* Wp = rw1 + (size_t)uv * Hh * Hh + (size_t)ks * 192 * Hh;
  __shared__ float Ast[16][68];
  __shared__ float Wst[16][68];
  const int t = threadIdx.x;
  const int row0 = blockIdx.x * 64, col0 = blockIdx.y * 64;
  const int tm = (t & 15) * 4, tn = (t >> 4) * 4;
  const int lr = t >> 2, lk = (t & 3) * 4;
  const int wk = t >> 4, wc = (t & 15) * 4;
  float acc[4][4] = {};
  const float* Arow = A + (size_t)(row0 + lr) * Hh + ks * 192 + lk;
  for (int k0 = 0; k0 < 192; k0 += 16) {
    float4 av = *(const float4*)(Arow + k0);
    Ast[lk + 0][lr] = av.x; Ast[lk + 1][lr] = av.y;
    Ast[lk + 2][lr] = av.z; Ast[lk + 3][lr] = av.w;
    *(float4*)&Wst[wk][wc] = *(const float4*)(Wp + (size_t)(k0 + wk) * Hh + col0 + wc);
    __syncthreads();
#pragma unroll
    for (int kk = 0; kk < 16; ++kk) {
      const float4 a = *(const float4*)&Ast[kk][tm];
      const float4 b = *(const float4*)&Wst[kk][tn];
      acc[0][0] = fmaf(a.x, b.x, acc[0][0]); acc[0][1] = fmaf(a.x, b.y, acc[0][1]);
      acc[0][2] = fmaf(a.x, b.z, acc[0][2]); acc[0][3] = fmaf(a.x, b.w, acc[0][3]);
      acc[1][0] = fmaf(a.y, b.x, acc[1][0]); acc[1][1] = fmaf(a.y, b.y, acc[1][1]);
      acc[1][2] = fmaf(a.y, b.z, acc[1][2]); acc[1][3] = fmaf(a.y, b.w, acc[1][3]);
      acc[2][0] = fmaf(a.z, b.x, acc[2][0]); acc[2][1] = fmaf(a.z, b.y, acc[2][1]);
      acc[2][2] = fmaf(a.z, b.z, acc[2][2]); acc[2][3] = fmaf(a.z, b.w, acc[2][3]);
      acc[3][0] = fmaf(a.w, b.x, acc[3][0]); acc[3][1] = fmaf(a.w, b.y, acc[3][1]);
      acc[3][2] = fmaf(a.w, b.z, acc[3][2]); acc[3][3] = fmaf(a.w, b.w, acc[3][3]);
    }
    __syncthreads();
  }
  float* out = part + ((size_t)ks * 2 + uv) * (512 * Hh);
#pragma unroll
  for (int i = 0; i < 4; ++i) {
    float4 o; o.x = acc[i][0]; o.y = acc[i][1]; o.z = acc[i][2]; o.w = acc[i][3];
    *(float4*)(out + (size_t)(row0 + tm + i) * Hh + col0 + tn) = o;
  }
}

// UV[i] = sum of 4 K-split partials
__global__ __launch_bounds__(256) void uv_reduce(const float* __restrict__ part,
                                                 float* __restrict__ uv) {
  const int i = blockIdx.x * 256 + threadIdx.x;   // float4 idx, 196608 total
  const float4* p = (const float4*)part;
  float4 a = p[i], b = p[i + 196608], c = p[i + 2 * 196608], d = p[i + 3 * 196608];
  float4 o;
  o.x = (a.x + b.x) + (c.x + d.x);
  o.y = (a.y + b.y) + (c.y + d.y);
  o.z = (a.z + b.z) + (c.z + d.z);
  o.w = (a.w + b.w) + (c.w + d.w);
  ((float4*)uv)[i] = o;
}

// ---------------------------------------------------------------------------
// In-place inclusive scan of Pc along c, per (b,h). Block = (b, 64 h-values).
// ---------------------------------------------------------------------------
__global__ __launch_bounds__(256) void chunk_scan(float* __restrict__ Pc) {
  __shared__ float tile[NC][64];
  const int b = blockIdx.y;
  const int h0 = blockIdx.x * 64;
  float* base = Pc + (size_t)b * NC * Hh + h0;
  const int l = threadIdx.x & 63, g = threadIdx.x >> 6;
#pragma unroll 4
  for (int c = g * 64; c < g * 64 + 64; ++c)
    tile[c][l] = base[(size_t)c * Hh + l];
  __syncthreads();
  float run = 0.f;
#pragma unroll 4
  for (int c = g * 64; c < g * 64 + 64; ++c) {
    run += tile[c][l];
    tile[c][l] = run;
  }
  __syncthreads();
  float off = 0.f;
#pragma unroll
  for (int gg = 0; gg < 3; ++gg)
    if (gg < g) off += tile[gg * 64 + 63][l];
  __syncthreads();
  if (g > 0) {
#pragma unroll 4
    for (int c = g * 64; c < g * 64 + 64; ++c)
      tile[c][l] += off;
  }
  __syncthreads();
#pragma unroll 4
  for (int c = g * 64; c < g * 64 + 64; ++c)
    base[(size_t)c * Hh + l] = tile[c][l];
}

// ---------------------------------------------------------------------------
// entity_reprs: O(1) chunk-range via inclusive prefix + <=30 edge rows.
// ---------------------------------------------------------------------------
__global__ __launch_bounds__(192) void entity_reprs_k(const float* __restrict__ seq,
                                                      const float* __restrict__ Pc,
                                                      const int* __restrict__ spans,
                                                      float* __restrict__ reprs) {
  const int bn = blockIdx.x;
  const int b = bn >> 6;
  const int start = spans[bn * 2], end = spans[bn * 2 + 1];
  const int cnt = max(end - start, 1);
  const float inv = 1.0f / (float)cnt;
  const int cs = (start + CH - 1) >> 4, ce = end >> 4;
  const float* seqb = seq + (size_t)b * Ss * Hh;
  const float4* Pcb = (const float4*)(Pc + (size_t)b * NC * Hh);
  const int t = threadIdx.x;  // 192 x float4 = 768
  float4 acc = {0.f, 0.f, 0.f, 0.f};
  if (cs <= ce) {
    if (cs < ce) {
      float4 hi = Pcb[(size_t)(ce - 1) * 192 + t];
      acc.x += hi.x; acc.y += hi.y; acc.z += hi.z; acc.w += hi.w;
      if (cs > 0) {
        float4 lo = Pcb[(size_t)(cs - 1) * 192 + t];
        acc.x -= lo.x; acc.y -= lo.y; acc.z -= lo.z; acc.w -= lo.w;
      }
    }
    for (int s = start; s < cs * CH; ++s) {
      float4 v = ((const float4*)(seqb + (size_t)s * Hh))[t];
      acc.x += v.x; acc.y += v.y; acc.z += v.z; acc.w += v.w;
    }
    for (int s = ce * CH; s < end; ++s) {
      float4 v = ((const float4*)(seqb + (size_t)s * Hh))[t];
      acc.x += v.x; acc.y += v.y; acc.z += v.z; acc.w += v.w;
    }
  } else {
    for (int s = start; s < end; ++s) {
      float4 v = ((const float4*)(seqb + (size_t)s * Hh))[t];
      acc.x += v.x; acc.y += v.y; acc.z += v.z; acc.w += v.w;
    }
  }
  float4 o; o.x = acc.x * inv; o.y = acc.y * inv; o.z = acc.z * inv; o.w = acc.w * inv;
  ((float4*)(reprs + (size_t)bn * Hh))[t] = o;
}

// ---------------------------------------------------------------------------
// pooled argmax: one block per entity (512 blocks, 4 waves).
// ---------------------------------------------------------------------------
__global__ __launch_bounds__(256) void pooled_argmax(const float* __restrict__ elog,
                                                     const int* __restrict__ spans,
                                                     float* __restrict__ etypes) {
  __shared__ float red[4][Ee];
  const int bn = blockIdx.x;
  const int b = bn >> 6;
  const int start = spans[bn * 2], end = spans[bn * 2 + 1];
  const int t = threadIdx.x, lane = t & 63, w = t >> 6;
  float acc[Ee];
#pragma unroll
  for (int e = 0; e < Ee; ++e) acc[e] = 0.f;
  const float* p = elog + (size_t)b * Ss * Ee;
  for (int s = start + t; s < end; s += 256) {
    const float* q = p + (size_t)s * Ee;
#pragma unroll
    for (int e = 0; e < Ee; ++e) acc[e] += q[e];
  }
#pragma unroll
  for (int off = 32; off; off >>= 1)
#pragma unroll
    for (int e = 0; e < Ee; ++e) acc[e] += __shfl_down(acc[e], off);
  if (lane == 0) {
#pragma unroll
    for (int e = 0; e < Ee; ++e) red[w][e] = acc[e];
  }
  __syncthreads();
  if (t == 0) {
    int best = 0; float bv = -1e30f;
#pragma unroll
    for (int e = 0; e < Ee; ++e) {
      float v = red[0][e] + red[1][e] + red[2][e] + red[3][e];
      if (v > bv) { bv = v; best = e; }
    }
    etypes[bn] = (float)best;
  }
}

// ---------------------------------------------------------------------------
// relations: one wave per (b,p). rw2 + rb1 cached in LDS (stride-11 pad so
// the k-strided read is 2-way max). 4 waves/block share the staging.
// ---------------------------------------------------------------------------
__global__ __launch_bounds__(256) void relations_k(const float* __restrict__ UV,
                                                   const float* __restrict__ rb1,
                                                   const float* __restrict__ rw2,
                                                   const float* __restrict__ rb2,
                                                   float* __restrict__ rlogits,
                                                   float* __restrict__ rtypes) {
  __shared__ float w2l[Hh * 11];   // 33792 B, [k*11 + r]
  __shared__ float b1l[Hh];        //  3072 B
  const int t = threadIdx.x;
  for (int i = t; i < Hh * Rr; i += 256) {
    const int k = i / Rr, r = i - k * Rr;
    w2l[k * 11 + r] = rw2[i];
  }
  for (int i = t; i < Hh; i += 256) b1l[i] = rb1[i];
  __syncthreads();

  const int p = blockIdx.x * 4 + (t >> 6);
  const int lane = t & 63;
  const int b = p / Pp, pp = p % Pp;
  int i = 0, off = 0;
  while (off + (Nn_ENT - 1 - i) <= pp) { off += Nn_ENT - 1 - i; ++i; }
  const int j = i + 1 + (pp - off);
  const float* u = UV + ((size_t)b * Nn_ENT + i) * Hh;
  const float* v = UV + (size_t)512 * Hh + ((size_t)b * Nn_ENT + j) * Hh;
  float acc[Rr];
#pragma unroll
  for (int r = 0; r < Rr; ++r) acc[r] = 0.f;
  for (int k = lane; k < Hh; k += 64) {
    float x = fmaxf(u[k] + v[k] + b1l[k], 0.f);
    const float* w = &w2l[k * 11];
#pragma unroll
    for (int r = 0; r < Rr; ++r) acc[r] = fmaf(x, w[r], acc[r]);
  }
#pragma unroll
  for (int off2 = 32; off2; off2 >>= 1)
#pragma unroll
    for (int r = 0; r < Rr; ++r) acc[r] += __shfl_down(acc[r], off2);
  if (lane == 0) {
    int best = 0; float bv = acc[0] + rb2[0];
    rlogits[(size_t)p * Rr + 0] = bv;
#pragma unroll
    for (int r = 1; r < Rr; ++r) {
      float val = acc[r] + rb2[r];
      rlogits[(size_t)p * Rr + r] = val;
      if (val > bv) { bv = val; best = r; }
    }
    rtypes[p] = (float)best;
  }
}

// ---------------------------------------------------------------------------
extern "C" void kernel_launch(void* const* d_in, const int* in_sizes, int n_in,
                              void* d_out, int out_size, void* d_ws, size_t ws_size,
                              hipStream_t stream) {
  const float* seq   = (const float*)d_in[0];
  const int*   spans = (const int*)d_in[2];
  const float* w1    = (const float*)d_in[3];
  const float* b1    = (const float*)d_in[4];
  const float* w2    = (const float*)d_in[5];
  const float* b2    = (const float*)d_in[6];
  const float* rw1   = (const float*)d_in[7];
  const float* rb1   = (const float*)d_in[8];
  const float* rw2   = (const float*)d_in[9];
  const float* rb2   = (const float*)d_in[10];

  float* out_elog = (float*)d_out;               // (B,S,E)   294912
  float* out_rlog = out_elog + 294912;           // (B,P,R)   161280
  float* out_repr = out_rlog + 161280;           // (B,N,H)   393216
  float* out_etyp = out_repr + 393216;           // (B,N)     512
  float* out_rtyp = out_etyp + 512;              // (B,P)     16128

  // workspace layout (bytes):
  unsigned short* ws_s16 = (unsigned short*)d_ws;                         // 50331648
  float*          ws_pc  = (float*)((char*)d_ws + 50331648);              //  6291456
  float*          ws_uv  = (float*)((char*)d_ws + 56623104);              //  3145728
  unsigned short* ws_wt  = (unsigned short*)((char*)d_ws + 59768832);     //   589824
  float*          ws_uvp = (float*)((char*)d_ws + 60358656);              // 12582912

  // 0) w1 -> bf16 transposed
  transpose_w1<<<dim3(12, 6), 256, 0, stream>>>(w1, ws_wt);
  // 1) seq -> bf16 + chunk sums (single streaming pass)
  seq_prep<<<dim3(NC, Bb), 192, 0, stream>>>(seq, ws_s16, ws_pc);
  // 2) elog = relu(seq16 @ w1 + b1) @ w2 + b2  (fused, swizzled LDS)
  gemm1_fused<<<512, 512, 0, stream>>>(ws_s16, ws_wt, b1, w2, b2, out_elog);
  // 3) prefix scan of chunk sums
  chunk_scan<<<dim3(Hh / 64, Bb), 256, 0, stream>>>(ws_pc);
  // 4) entity_reprs (prefix diff + edge rows)
  entity_reprs_k<<<512, 192, 0, stream>>>(seq, ws_pc, spans, out_repr);
  // 5) U,V = reprs @ rw1 halves: split-K (4) + reduce
  gemm_uv_splitk<<<dim3(8, 12, 8), 256, 0, stream>>>(out_repr, rw1, ws_uvp);
  uv_reduce<<<768, 256, 0, stream>>>(ws_uvp, ws_uv);
  // 6) entity_types via pooled-logits argmax
  pooled_argmax<<<512, 256, 0, stream>>>(out_elog, spans, out_etyp);
  // 7) relation logits + types
  relations_k<<<4032, 256, 0, stream>>>(ws_uv, rb1, rw2, rb2, out_rlog, out_rtyp);
}